// Round 1
// baseline (9492.648 us; speedup 1.0000x reference)
//
#include <hip/hip_runtime.h>
#include <hip/hip_bf16.h>
#include <math.h>

// Problem constants
#define S 2048
#define HID 2048
#define NH 16
#define KVH 8
#define HD 128
#define EPS 1e-6f
#define QK_SCALE 11.313708498984760390f  // 1/SCALING = sqrt(128)

// ---------------------------------------------------------------------------
// Simple fp32 tiled GEMM: C[M,N] = A[M,K] @ B[K,N], all row-major.
// 64x64 tile, K-tile 16, 256 threads, 4x4 micro-tile per thread.
// M,N multiples of 64; K multiple of 16 (true for all calls here).
// ---------------------------------------------------------------------------
#define GT_M 64
#define GT_N 64
#define GT_K 16

__global__ __launch_bounds__(256) void gemm_f32(const float* __restrict__ A,
                                                const float* __restrict__ B,
                                                float* __restrict__ C,
                                                int M, int N, int K) {
  // As padded to 68 floats/row: keeps 16B alignment for ds_read_b128 and
  // spreads the transposed-store bank pattern (2-way max, free on wave64).
  __shared__ float As[GT_K][GT_M + 4];
  __shared__ float Bs[GT_K][GT_N];

  const int tid = threadIdx.x;
  const int tx = tid & 15;   // -> n
  const int ty = tid >> 4;   // -> m
  const int m0 = blockIdx.y * GT_M;
  const int n0 = blockIdx.x * GT_N;

  // loader coords
  const int a_m = tid >> 2;          // 0..63
  const int a_k = (tid & 3) * 4;     // 0,4,8,12
  const int b_k = tid >> 4;          // 0..15
  const int b_n = (tid & 15) * 4;    // 0..60

  float acc[4][4] = {};

  for (int k0 = 0; k0 < K; k0 += GT_K) {
    const float4 av = *(const float4*)(A + (size_t)(m0 + a_m) * K + (k0 + a_k));
    As[a_k + 0][a_m] = av.x;
    As[a_k + 1][a_m] = av.y;
    As[a_k + 2][a_m] = av.z;
    As[a_k + 3][a_m] = av.w;
    const float4 bv = *(const float4*)(B + (size_t)(k0 + b_k) * N + (n0 + b_n));
    *(float4*)&Bs[b_k][b_n] = bv;
    __syncthreads();

#pragma unroll
    for (int kk = 0; kk < GT_K; ++kk) {
      float a[4], b[4];
#pragma unroll
      for (int i = 0; i < 4; ++i) a[i] = As[kk][ty * 4 + i];
#pragma unroll
      for (int j = 0; j < 4; ++j) b[j] = Bs[kk][tx * 4 + j];
#pragma unroll
      for (int i = 0; i < 4; ++i)
#pragma unroll
        for (int j = 0; j < 4; ++j) acc[i][j] += a[i] * b[j];
    }
    __syncthreads();
  }

#pragma unroll
  for (int i = 0; i < 4; ++i) {
    float4 o = make_float4(acc[i][0], acc[i][1], acc[i][2], acc[i][3]);
    *(float4*)(C + (size_t)(m0 + ty * 4 + i) * N + (n0 + tx * 4)) = o;
  }
}

// ---------------------------------------------------------------------------
// Fused per-head RMSNorm + RoPE, in place.
// x layout: [s][h*HD + d], grid = (S, nheads), block = 128 (= HD).
// out[d] = xn[d]*cos[s,d] + rot(xn)[d]*sin[s,d];  rot: [-x2, x1] halves of 64.
// ---------------------------------------------------------------------------
__global__ __launch_bounds__(128) void rmsnorm_rope(float* __restrict__ x,
                                                    const float* __restrict__ cosb,
                                                    const float* __restrict__ sinb,
                                                    int nheads) {
  const int s = blockIdx.x;
  const int h = blockIdx.y;
  const int t = threadIdx.x;  // 0..127 = d

  float* row = x + ((size_t)s * nheads + h) * HD;
  const float v = row[t];

  __shared__ float sv[HD];
  __shared__ float red[HD];
  sv[t] = v;
  red[t] = v * v;
  __syncthreads();
#pragma unroll
  for (int off = 64; off > 0; off >>= 1) {
    if (t < off) red[t] += red[t + off];
    __syncthreads();
  }
  const float r = rsqrtf(red[0] / (float)HD + EPS);

  const float xn = v * r;
  const float other = sv[t ^ 64] * r;          // partner element, normalized
  const float rot = (t < 64) ? -other : other; // rotate_half
  const float c = cosb[(size_t)s * HD + t];
  const float sn = sinb[(size_t)s * HD + t];
  row[t] = xn * c + rot * sn;
}

// ---------------------------------------------------------------------------
// Attention: one block per (q-row, head). 128 threads.
// Phase 1: 16 keys/thread -> scores in LDS; softmax reduce.
// Phase 2: thread t owns output dim t; sums probs[k]*V[k][t] (coalesced).
// GQA: q head h uses kv head h>>1.
// ---------------------------------------------------------------------------
__global__ __launch_bounds__(128) void attn_fp32(const float* __restrict__ q,
                                                 const float* __restrict__ k,
                                                 const float* __restrict__ v,
                                                 float* __restrict__ out) {
  const int sq = blockIdx.x;
  const int h = blockIdx.y;
  const int kvh = h >> 1;
  const int t = threadIdx.x;

  __shared__ float qs[HD];
  __shared__ float probs[S];
  __shared__ float red[128];

  qs[t] = q[((size_t)sq * NH + h) * HD + t] * QK_SCALE;
  __syncthreads();

  float scores[16];
  float lmax = -1e30f;
#pragma unroll 1
  for (int i = 0; i < 16; ++i) {
    const int key = t + i * 128;
    const float* kr = k + ((size_t)key * KVH + kvh) * HD;
    float acc = 0.f;
#pragma unroll
    for (int d = 0; d < HD; d += 4) {
      const float4 kv4 = *(const float4*)(kr + d);
      const float4 qv4 = *(const float4*)(&qs[d]);
      acc += qv4.x * kv4.x + qv4.y * kv4.y + qv4.z * kv4.z + qv4.w * kv4.w;
    }
    scores[i] = acc;
    lmax = fmaxf(lmax, acc);
  }

  // block max
  red[t] = lmax;
  __syncthreads();
#pragma unroll
  for (int off = 64; off > 0; off >>= 1) {
    if (t < off) red[t] = fmaxf(red[t], red[t + off]);
    __syncthreads();
  }
  const float m = red[0];
  __syncthreads();

  float lsum = 0.f;
#pragma unroll
  for (int i = 0; i < 16; ++i) {
    const float e = __expf(scores[i] - m);
    probs[t + i * 128] = e;
    lsum += e;
  }
  red[t] = lsum;
  __syncthreads();
#pragma unroll
  for (int off = 64; off > 0; off >>= 1) {
    if (t < off) red[t] += red[t + off];
    __syncthreads();
  }
  const float inv = 1.f / red[0];

  // Phase 2: output dim t
  float accv = 0.f;
  const float* vb = v + (size_t)kvh * HD + t;
#pragma unroll 4
  for (int key = 0; key < S; ++key) {
    accv += probs[key] * vb[(size_t)key * (KVH * HD)];
  }
  out[((size_t)sq * NH + h) * HD + t] = accv * inv;
}

// ---------------------------------------------------------------------------
extern "C" void kernel_launch(void* const* d_in, const int* in_sizes, int n_in,
                              void* d_out, int out_size, void* d_ws, size_t ws_size,
                              hipStream_t stream) {
  const float* hidden = (const float*)d_in[0];  // [S][HID]
  const float* cosb   = (const float*)d_in[1];  // [S][HD]
  const float* sinb   = (const float*)d_in[2];  // [S][HD]
  const float* wq     = (const float*)d_in[3];  // [HID][NH*HD]
  const float* wk     = (const float*)d_in[4];  // [HID][KVH*HD]
  const float* wv     = (const float*)d_in[5];  // [HID][KVH*HD]
  const float* wo     = (const float*)d_in[6];  // [NH*HD][HID]
  float* out = (float*)d_out;                   // [S][HID]

  // workspace layout (floats): q 4M, k 2M, v 2M, attn 4M  => 48 MB
  float* q_buf = (float*)d_ws;
  float* k_buf = q_buf + (size_t)S * NH * HD;
  float* v_buf = k_buf + (size_t)S * KVH * HD;
  float* a_buf = v_buf + (size_t)S * KVH * HD;

  dim3 blk(256);
  // QKV projections
  gemm_f32<<<dim3((NH * HD) / GT_N, S / GT_M), blk, 0, stream>>>(hidden, wq, q_buf, S, NH * HD, HID);
  gemm_f32<<<dim3((KVH * HD) / GT_N, S / GT_M), blk, 0, stream>>>(hidden, wk, k_buf, S, KVH * HD, HID);
  gemm_f32<<<dim3((KVH * HD) / GT_N, S / GT_M), blk, 0, stream>>>(hidden, wv, v_buf, S, KVH * HD, HID);

  // RMSNorm + RoPE (in place) on q and k
  rmsnorm_rope<<<dim3(S, NH), dim3(128), 0, stream>>>(q_buf, cosb, sinb, NH);
  rmsnorm_rope<<<dim3(S, KVH), dim3(128), 0, stream>>>(k_buf, cosb, sinb, KVH);

  // Attention -> a_buf laid out [s][h*HD+d]
  attn_fp32<<<dim3(S, NH), dim3(128), 0, stream>>>(q_buf, k_buf, v_buf, a_buf);

  // Output projection
  gemm_f32<<<dim3(HID / GT_N, S / GT_M), blk, 0, stream>>>(a_buf, wo, out, S, HID, HID);
}

// Round 2
// 1403.698 us; speedup vs baseline: 6.7626x; 6.7626x over previous
//
#include <hip/hip_runtime.h>
#include <hip/hip_bf16.h>
#include <math.h>

// Problem constants
#define S 2048
#define HID 2048
#define NH 16
#define KVH 8
#define HD 128
#define EPS 1e-6f
#define QK_SCALE 11.313708498984760390f  // 1/SCALING = sqrt(128)

// ---------------------------------------------------------------------------
// Simple fp32 tiled GEMM: C[M,N] = A[M,K] @ B[K,N], all row-major.
// 64x64 tile, K-tile 16, 256 threads, 4x4 micro-tile per thread.
// ---------------------------------------------------------------------------
#define GT_M 64
#define GT_N 64
#define GT_K 16

__global__ __launch_bounds__(256) void gemm_f32(const float* __restrict__ A,
                                                const float* __restrict__ B,
                                                float* __restrict__ C,
                                                int M, int N, int K) {
  __shared__ float As[GT_K][GT_M + 4];
  __shared__ float Bs[GT_K][GT_N];

  const int tid = threadIdx.x;
  const int tx = tid & 15;   // -> n
  const int ty = tid >> 4;   // -> m
  const int m0 = blockIdx.y * GT_M;
  const int n0 = blockIdx.x * GT_N;

  const int a_m = tid >> 2;          // 0..63
  const int a_k = (tid & 3) * 4;     // 0,4,8,12
  const int b_k = tid >> 4;          // 0..15
  const int b_n = (tid & 15) * 4;    // 0..60

  float acc[4][4] = {};

  for (int k0 = 0; k0 < K; k0 += GT_K) {
    const float4 av = *(const float4*)(A + (size_t)(m0 + a_m) * K + (k0 + a_k));
    As[a_k + 0][a_m] = av.x;
    As[a_k + 1][a_m] = av.y;
    As[a_k + 2][a_m] = av.z;
    As[a_k + 3][a_m] = av.w;
    const float4 bv = *(const float4*)(B + (size_t)(k0 + b_k) * N + (n0 + b_n));
    *(float4*)&Bs[b_k][b_n] = bv;
    __syncthreads();

#pragma unroll
    for (int kk = 0; kk < GT_K; ++kk) {
      float a[4], b[4];
#pragma unroll
      for (int i = 0; i < 4; ++i) a[i] = As[kk][ty * 4 + i];
#pragma unroll
      for (int j = 0; j < 4; ++j) b[j] = Bs[kk][tx * 4 + j];
#pragma unroll
      for (int i = 0; i < 4; ++i)
#pragma unroll
        for (int j = 0; j < 4; ++j) acc[i][j] += a[i] * b[j];
    }
    __syncthreads();
  }

#pragma unroll
  for (int i = 0; i < 4; ++i) {
    float4 o = make_float4(acc[i][0], acc[i][1], acc[i][2], acc[i][3]);
    *(float4*)(C + (size_t)(m0 + ty * 4 + i) * N + (n0 + tx * 4)) = o;
  }
}

// ---------------------------------------------------------------------------
// Fused per-head RMSNorm + RoPE, in place.
// ---------------------------------------------------------------------------
__global__ __launch_bounds__(128) void rmsnorm_rope(float* __restrict__ x,
                                                    const float* __restrict__ cosb,
                                                    const float* __restrict__ sinb,
                                                    int nheads) {
  const int s = blockIdx.x;
  const int h = blockIdx.y;
  const int t = threadIdx.x;  // 0..127 = d

  float* row = x + ((size_t)s * nheads + h) * HD;
  const float v = row[t];

  __shared__ float sv[HD];
  __shared__ float red[HD];
  sv[t] = v;
  red[t] = v * v;
  __syncthreads();
#pragma unroll
  for (int off = 64; off > 0; off >>= 1) {
    if (t < off) red[t] += red[t + off];
    __syncthreads();
  }
  const float r = rsqrtf(red[0] / (float)HD + EPS);

  const float xn = v * r;
  const float other = sv[t ^ 64] * r;          // partner element, normalized
  const float rot = (t < 64) ? -other : other; // rotate_half
  const float c = cosb[(size_t)s * HD + t];
  const float sn = sinb[(size_t)s * HD + t];
  row[t] = xn * c + rot * sn;
}

// ---------------------------------------------------------------------------
// Flash attention, fp32 VALU, online softmax.
// grid = (S/FA_M, NH), block = 256.
// Per block: Q tile 128 rows x 128 d in LDS (scaled), loop over 32 key tiles
// of 64 keys: S = Q K^T (8x4 micro-tile/thread), online softmax (row stats
// shfl-reduced over the 16 lanes sharing ty), P through LDS, O += P V
// (8x8 micro-tile/thread). GQA: q head h -> kv head h>>1.
// LDS: Qs 66K + KVs 33K (K then V reuse same buffer) + Ps 34K = 133 KB
// -> 1 block/CU, 4 waves; per-thread FMA density hides latency.
// ---------------------------------------------------------------------------
#define FA_M 128
#define FA_N 64

__global__ __launch_bounds__(256, 1) void attn_flash_f32(const float* __restrict__ q,
                                                         const float* __restrict__ k,
                                                         const float* __restrict__ v,
                                                         float* __restrict__ out) {
  const int h = blockIdx.y;
  const int kvh = h >> 1;
  const int m0 = blockIdx.x * FA_M;
  const int tid = threadIdx.x;
  const int tx = tid & 15;   // col group
  const int ty = tid >> 4;   // row group (0..15)

  __shared__ float Qs[FA_M][HD + 4];    // [m][d], rows: ty + 16*i
  __shared__ float KVs[FA_N][HD + 4];   // K tile [n][d], then V tile [key][d]
  __shared__ float Ps[FA_M][FA_N + 4];  // probs [m][key]

  // ---- load Q tile, pre-scaled ----
  for (int idx = tid; idx < FA_M * (HD / 4); idx += 256) {
    const int r = idx >> 5;             // 32 float4 per row
    const int c4 = (idx & 31) * 4;
    float4 qv = *(const float4*)(q + ((size_t)(m0 + r) * NH + h) * HD + c4);
    qv.x *= QK_SCALE; qv.y *= QK_SCALE; qv.z *= QK_SCALE; qv.w *= QK_SCALE;
    *(float4*)&Qs[r][c4] = qv;
  }

  float m_i[8], l_i[8], O[8][8];
#pragma unroll
  for (int i = 0; i < 8; ++i) {
    m_i[i] = -1e30f;
    l_i[i] = 0.f;
#pragma unroll
    for (int j = 0; j < 8; ++j) O[i][j] = 0.f;
  }

  for (int n0 = 0; n0 < S; n0 += FA_N) {
    __syncthreads();  // prev PV done with KVs/Ps; Q store done (first iter)
    // ---- load K tile ----
    for (int idx = tid; idx < FA_N * (HD / 4); idx += 256) {
      const int r = idx >> 5;
      const int c4 = (idx & 31) * 4;
      *(float4*)&KVs[r][c4] =
          *(const float4*)(k + ((size_t)(n0 + r) * KVH + kvh) * HD + c4);
    }
    __syncthreads();

    // ---- S = Q K^T : rows m = ty+16i, cols n = tx+16j ----
    float s[8][4];
#pragma unroll
    for (int i = 0; i < 8; ++i)
#pragma unroll
      for (int j = 0; j < 4; ++j) s[i][j] = 0.f;

    for (int kk = 0; kk < HD; kk += 4) {
      float a[8][4], b[4][4];
#pragma unroll
      for (int i = 0; i < 8; ++i) {
        const float4 t4 = *(const float4*)&Qs[ty + 16 * i][kk];
        a[i][0] = t4.x; a[i][1] = t4.y; a[i][2] = t4.z; a[i][3] = t4.w;
      }
#pragma unroll
      for (int j = 0; j < 4; ++j) {
        const float4 t4 = *(const float4*)&KVs[tx + 16 * j][kk];
        b[j][0] = t4.x; b[j][1] = t4.y; b[j][2] = t4.z; b[j][3] = t4.w;
      }
#pragma unroll
      for (int i = 0; i < 8; ++i)
#pragma unroll
        for (int j = 0; j < 4; ++j)
#pragma unroll
          for (int t = 0; t < 4; ++t) s[i][j] += a[i][t] * b[j][t];
    }

    // ---- online softmax (row stats across the 16 lanes sharing ty) ----
    float p[8][4];
#pragma unroll
    for (int i = 0; i < 8; ++i) {
      float mt = fmaxf(fmaxf(s[i][0], s[i][1]), fmaxf(s[i][2], s[i][3]));
      mt = fmaxf(mt, __shfl_xor(mt, 1));
      mt = fmaxf(mt, __shfl_xor(mt, 2));
      mt = fmaxf(mt, __shfl_xor(mt, 4));
      mt = fmaxf(mt, __shfl_xor(mt, 8));
      const float mnew = fmaxf(m_i[i], mt);
      const float alpha = __expf(m_i[i] - mnew);
      m_i[i] = mnew;
      float ls = 0.f;
#pragma unroll
      for (int j = 0; j < 4; ++j) {
        p[i][j] = __expf(s[i][j] - mnew);
        ls += p[i][j];
      }
      ls += __shfl_xor(ls, 1);
      ls += __shfl_xor(ls, 2);
      ls += __shfl_xor(ls, 4);
      ls += __shfl_xor(ls, 8);
      l_i[i] = l_i[i] * alpha + ls;
#pragma unroll
      for (int jj = 0; jj < 8; ++jj) O[i][jj] *= alpha;
    }

    __syncthreads();  // everyone done reading K from KVs

    // ---- load V tile over KVs; write P to LDS ----
    for (int idx = tid; idx < FA_N * (HD / 4); idx += 256) {
      const int r = idx >> 5;
      const int c4 = (idx & 31) * 4;
      *(float4*)&KVs[r][c4] =
          *(const float4*)(v + ((size_t)(n0 + r) * KVH + kvh) * HD + c4);
    }
#pragma unroll
    for (int i = 0; i < 8; ++i)
#pragma unroll
      for (int j = 0; j < 4; ++j) Ps[ty + 16 * i][tx + 16 * j] = p[i][j];
    __syncthreads();

    // ---- O += P V : rows m = ty+16i, cols d = tx*8 + jj ----
    for (int kk = 0; kk < FA_N; kk += 4) {
      float pa[8][4];
#pragma unroll
      for (int i = 0; i < 8; ++i) {
        const float4 t4 = *(const float4*)&Ps[ty + 16 * i][kk];
        pa[i][0] = t4.x; pa[i][1] = t4.y; pa[i][2] = t4.z; pa[i][3] = t4.w;
      }
#pragma unroll
      for (int t = 0; t < 4; ++t) {
        const float4 v0 = *(const float4*)&KVs[kk + t][tx * 8];
        const float4 v1 = *(const float4*)&KVs[kk + t][tx * 8 + 4];
#pragma unroll
        for (int i = 0; i < 8; ++i) {
          const float av = pa[i][t];
          O[i][0] += av * v0.x; O[i][1] += av * v0.y;
          O[i][2] += av * v0.z; O[i][3] += av * v0.w;
          O[i][4] += av * v1.x; O[i][5] += av * v1.y;
          O[i][6] += av * v1.z; O[i][7] += av * v1.w;
        }
      }
    }
  }

  // ---- epilogue: normalize and store ----
#pragma unroll
  for (int i = 0; i < 8; ++i) {
    const float inv = 1.f / l_i[i];
    const int m = m0 + ty + 16 * i;
    float* op = out + ((size_t)m * NH + h) * HD + tx * 8;
    float4 o0 = make_float4(O[i][0] * inv, O[i][1] * inv, O[i][2] * inv, O[i][3] * inv);
    float4 o1 = make_float4(O[i][4] * inv, O[i][5] * inv, O[i][6] * inv, O[i][7] * inv);
    *(float4*)op = o0;
    *(float4*)(op + 4) = o1;
  }
}

// ---------------------------------------------------------------------------
extern "C" void kernel_launch(void* const* d_in, const int* in_sizes, int n_in,
                              void* d_out, int out_size, void* d_ws, size_t ws_size,
                              hipStream_t stream) {
  const float* hidden = (const float*)d_in[0];  // [S][HID]
  const float* cosb   = (const float*)d_in[1];  // [S][HD]
  const float* sinb   = (const float*)d_in[2];  // [S][HD]
  const float* wq     = (const float*)d_in[3];  // [HID][NH*HD]
  const float* wk     = (const float*)d_in[4];  // [HID][KVH*HD]
  const float* wv     = (const float*)d_in[5];  // [HID][KVH*HD]
  const float* wo     = (const float*)d_in[6];  // [NH*HD][HID]
  float* out = (float*)d_out;                   // [S][HID]

  float* q_buf = (float*)d_ws;
  float* k_buf = q_buf + (size_t)S * NH * HD;
  float* v_buf = k_buf + (size_t)S * KVH * HD;
  float* a_buf = v_buf + (size_t)S * KVH * HD;

  dim3 blk(256);
  gemm_f32<<<dim3((NH * HD) / GT_N, S / GT_M), blk, 0, stream>>>(hidden, wq, q_buf, S, NH * HD, HID);
  gemm_f32<<<dim3((KVH * HD) / GT_N, S / GT_M), blk, 0, stream>>>(hidden, wk, k_buf, S, KVH * HD, HID);
  gemm_f32<<<dim3((KVH * HD) / GT_N, S / GT_M), blk, 0, stream>>>(hidden, wv, v_buf, S, KVH * HD, HID);

  rmsnorm_rope<<<dim3(S, NH), dim3(128), 0, stream>>>(q_buf, cosb, sinb, NH);
  rmsnorm_rope<<<dim3(S, KVH), dim3(128), 0, stream>>>(k_buf, cosb, sinb, KVH);

  attn_flash_f32<<<dim3(S / FA_M, NH), blk, 0, stream>>>(q_buf, k_buf, v_buf, a_buf);

  gemm_f32<<<dim3(HID / GT_N, S / GT_M), blk, 0, stream>>>(a_buf, wo, out, S, HID, HID);
}

// Round 4
// 905.806 us; speedup vs baseline: 10.4798x; 1.5497x over previous
//
#include <hip/hip_runtime.h>
#include <hip/hip_bf16.h>
#include <math.h>

// Problem constants
#define S 2048
#define HID 2048
#define NH 16
#define KVH 8
#define HD 128
#define EPS 1e-6f
#define QK_SCALE 11.313708498984760390f  // 1/SCALING = sqrt(128)

typedef __attribute__((ext_vector_type(8))) short s16x8;
typedef __attribute__((ext_vector_type(4))) float f32x4;

__device__ __forceinline__ unsigned short f2bf(float f) {
  __hip_bfloat16 h = __float2bfloat16(f);
  return *(unsigned short*)&h;
}
__device__ __forceinline__ float bf2f(unsigned short u) {
  unsigned int x = ((unsigned int)u) << 16;
  return __builtin_bit_cast(float, x);
}

__device__ __forceinline__ void gload16(const void* g, void* l) {
  __builtin_amdgcn_global_load_lds(
      (const __attribute__((address_space(1))) void*)g,
      (__attribute__((address_space(3))) void*)l, 16, 0, 0);
}

// ---------------------------------------------------------------------------
// fp32 -> split bf16 (hi + lo) elementwise. 4 elems/thread.
// x = hi + lo exactly to ~2^-16 relative.
// ---------------------------------------------------------------------------
__global__ __launch_bounds__(256) void f32_to_bf16_split(const float* __restrict__ in,
                                                         unsigned short* __restrict__ hi,
                                                         unsigned short* __restrict__ lo,
                                                         int n4) {
  const int i = blockIdx.x * 256 + threadIdx.x;
  if (i < n4) {
    const float4 v = *(const float4*)(in + (size_t)i * 4);
    ushort4 h, l;
    h.x = f2bf(v.x); l.x = f2bf(v.x - bf2f(h.x));
    h.y = f2bf(v.y); l.y = f2bf(v.y - bf2f(h.y));
    h.z = f2bf(v.z); l.z = f2bf(v.z - bf2f(h.z));
    h.w = f2bf(v.w); l.w = f2bf(v.w - bf2f(h.w));
    *(ushort4*)(hi + (size_t)i * 4) = h;
    *(ushort4*)(lo + (size_t)i * 4) = l;
  }
}

// ---------------------------------------------------------------------------
// Transpose fp32 [K][N] -> bf16 [N][K], plain (hi only).
// ---------------------------------------------------------------------------
__global__ __launch_bounds__(256) void transpose_to_bf16(const float* __restrict__ in,
                                                         unsigned short* __restrict__ out,
                                                         int K, int N) {
  __shared__ float t[64][65];
  const int n0 = blockIdx.x * 64;
  const int k0 = blockIdx.y * 64;
  const int tid = threadIdx.x;

  for (int idx = tid; idx < 64 * 16; idx += 256) {
    const int r = idx >> 4;
    const int c4 = (idx & 15) * 4;
    const float4 v = *(const float4*)(in + (size_t)(k0 + r) * N + n0 + c4);
    t[r][c4 + 0] = v.x; t[r][c4 + 1] = v.y; t[r][c4 + 2] = v.z; t[r][c4 + 3] = v.w;
  }
  __syncthreads();
  for (int idx = tid; idx < 64 * 16; idx += 256) {
    const int a = idx >> 4;
    const int b4 = (idx & 15) * 4;
    ushort4 u;
    u.x = f2bf(t[b4 + 0][a]); u.y = f2bf(t[b4 + 1][a]);
    u.z = f2bf(t[b4 + 2][a]); u.w = f2bf(t[b4 + 3][a]);
    *(ushort4*)(out + (size_t)(n0 + a) * K + k0 + b4) = u;
  }
}

// ---------------------------------------------------------------------------
// Transpose fp32 [K][N] -> split bf16 hi/lo [N][K].
// ---------------------------------------------------------------------------
__global__ __launch_bounds__(256) void transpose_to_bf16_split(const float* __restrict__ in,
                                                               unsigned short* __restrict__ ohi,
                                                               unsigned short* __restrict__ olo,
                                                               int K, int N) {
  __shared__ float t[64][65];
  const int n0 = blockIdx.x * 64;
  const int k0 = blockIdx.y * 64;
  const int tid = threadIdx.x;

  for (int idx = tid; idx < 64 * 16; idx += 256) {
    const int r = idx >> 4;
    const int c4 = (idx & 15) * 4;
    const float4 v = *(const float4*)(in + (size_t)(k0 + r) * N + n0 + c4);
    t[r][c4 + 0] = v.x; t[r][c4 + 1] = v.y; t[r][c4 + 2] = v.z; t[r][c4 + 3] = v.w;
  }
  __syncthreads();
  for (int idx = tid; idx < 64 * 16; idx += 256) {
    const int a = idx >> 4;
    const int b4 = (idx & 15) * 4;
    ushort4 h, l;
#pragma unroll
    for (int q = 0; q < 4; ++q) {
      const float v = t[b4 + q][a];
      const unsigned short hu = f2bf(v);
      const unsigned short lu = f2bf(v - bf2f(hu));
      ((unsigned short*)&h)[q] = hu;
      ((unsigned short*)&l)[q] = lu;
    }
    *(ushort4*)(ohi + (size_t)(n0 + a) * K + k0 + b4) = h;
    *(ushort4*)(olo + (size_t)(n0 + a) * K + k0 + b4) = l;
  }
}

// ---------------------------------------------------------------------------
// Plain bf16 MFMA GEMM (m97 structure): C[M][ldc] = A[M][K] * Bt[N][K]^T.
// OT = float (fp32 store) or unsigned short (bf16 store).
// ---------------------------------------------------------------------------
#define BM 128
#define BN 128
#define BK 32

template <typename OT>
__global__ __launch_bounds__(256) void gemm_bf16_bt(const unsigned short* __restrict__ A,
                                                    const unsigned short* __restrict__ Bt,
                                                    OT* __restrict__ C,
                                                    int M, int N, int K, int ldc) {
  __shared__ unsigned short As[BM * BK];
  __shared__ unsigned short Bs[BN * BK];

  const int tid = threadIdx.x;
  const int lane = tid & 63;
  const int wave = tid >> 6;
  const int m0 = blockIdx.y * BM;
  const int n0 = blockIdx.x * BN;

  const int qm = (wave >> 1) * 64;
  const int qn = (wave & 1) * 64;
  const int l15 = lane & 15;
  const int quad = lane >> 4;

  const int st_row = lane >> 2;
  const int st_col = (lane & 3) * 8;

  f32x4 acc[4][4] = {};

  for (int k0 = 0; k0 < K; k0 += BK) {
#pragma unroll
    for (int p = 0; p < 2; ++p) {
      const int rb = p * 64 + wave * 16;
      gload16(A + (size_t)(m0 + rb + st_row) * K + k0 + st_col, &As[rb * BK]);
      gload16(Bt + (size_t)(n0 + rb + st_row) * K + k0 + st_col, &Bs[rb * BK]);
    }
    __syncthreads();

    s16x8 a[4], b[4];
#pragma unroll
    for (int i = 0; i < 4; ++i)
      a[i] = *(const s16x8*)&As[(qm + i * 16 + l15) * BK + quad * 8];
#pragma unroll
    for (int j = 0; j < 4; ++j)
      b[j] = *(const s16x8*)&Bs[(qn + j * 16 + l15) * BK + quad * 8];
#pragma unroll
    for (int i = 0; i < 4; ++i)
#pragma unroll
      for (int j = 0; j < 4; ++j)
        acc[i][j] = __builtin_amdgcn_mfma_f32_16x16x32_bf16(a[i], b[j], acc[i][j], 0, 0, 0);
    __syncthreads();
  }

#pragma unroll
  for (int i = 0; i < 4; ++i) {
    const int row_base = m0 + qm + i * 16 + quad * 4;
#pragma unroll
    for (int j = 0; j < 4; ++j) {
      const int col = n0 + qn + j * 16 + l15;
#pragma unroll
      for (int r = 0; r < 4; ++r) {
        if constexpr (sizeof(OT) == 2)
          C[(size_t)(row_base + r) * ldc + col] = (OT)f2bf(acc[i][j][r]);
        else
          C[(size_t)(row_base + r) * ldc + col] = acc[i][j][r];
      }
    }
  }
}

// ---------------------------------------------------------------------------
// Split-precision bf16 MFMA GEMM: C = (Ahi+Alo) * (Bhi+Blo)^T, dropping lo*lo.
// 3 MFMAs per fragment pair -> ~2^-16 relative error (fp32-grade for scores).
// ---------------------------------------------------------------------------
__global__ __launch_bounds__(256) void gemm_split_bt(const unsigned short* __restrict__ Ahi,
                                                     const unsigned short* __restrict__ Alo,
                                                     const unsigned short* __restrict__ Bhi,
                                                     const unsigned short* __restrict__ Blo,
                                                     float* __restrict__ C,
                                                     int M, int N, int K, int ldc) {
  __shared__ unsigned short AsH[BM * BK];
  __shared__ unsigned short AsL[BM * BK];
  __shared__ unsigned short BsH[BN * BK];
  __shared__ unsigned short BsL[BN * BK];

  const int tid = threadIdx.x;
  const int lane = tid & 63;
  const int wave = tid >> 6;
  const int m0 = blockIdx.y * BM;
  const int n0 = blockIdx.x * BN;

  const int qm = (wave >> 1) * 64;
  const int qn = (wave & 1) * 64;
  const int l15 = lane & 15;
  const int quad = lane >> 4;

  const int st_row = lane >> 2;
  const int st_col = (lane & 3) * 8;

  f32x4 acc[4][4] = {};

  for (int k0 = 0; k0 < K; k0 += BK) {
#pragma unroll
    for (int p = 0; p < 2; ++p) {
      const int rb = p * 64 + wave * 16;
      const size_t aoff = (size_t)(m0 + rb + st_row) * K + k0 + st_col;
      const size_t boff = (size_t)(n0 + rb + st_row) * K + k0 + st_col;
      gload16(Ahi + aoff, &AsH[rb * BK]);
      gload16(Alo + aoff, &AsL[rb * BK]);
      gload16(Bhi + boff, &BsH[rb * BK]);
      gload16(Blo + boff, &BsL[rb * BK]);
    }
    __syncthreads();

    s16x8 ah[4], al[4], bh[4], bl[4];
#pragma unroll
    for (int i = 0; i < 4; ++i) {
      const int ro = (qm + i * 16 + l15) * BK + quad * 8;
      ah[i] = *(const s16x8*)&AsH[ro];
      al[i] = *(const s16x8*)&AsL[ro];
    }
#pragma unroll
    for (int j = 0; j < 4; ++j) {
      const int ro = (qn + j * 16 + l15) * BK + quad * 8;
      bh[j] = *(const s16x8*)&BsH[ro];
      bl[j] = *(const s16x8*)&BsL[ro];
    }
#pragma unroll
    for (int i = 0; i < 4; ++i)
#pragma unroll
      for (int j = 0; j < 4; ++j) {
        acc[i][j] = __builtin_amdgcn_mfma_f32_16x16x32_bf16(ah[i], bh[j], acc[i][j], 0, 0, 0);
        acc[i][j] = __builtin_amdgcn_mfma_f32_16x16x32_bf16(ah[i], bl[j], acc[i][j], 0, 0, 0);
        acc[i][j] = __builtin_amdgcn_mfma_f32_16x16x32_bf16(al[i], bh[j], acc[i][j], 0, 0, 0);
      }
    __syncthreads();
  }

#pragma unroll
  for (int i = 0; i < 4; ++i) {
    const int row_base = m0 + qm + i * 16 + quad * 4;
#pragma unroll
    for (int j = 0; j < 4; ++j) {
      const int col = n0 + qn + j * 16 + l15;
#pragma unroll
      for (int r = 0; r < 4; ++r)
        C[(size_t)(row_base + r) * ldc + col] = acc[i][j][r];
    }
  }
}

// ---------------------------------------------------------------------------
// Fused per-head RMSNorm + RoPE in place on packed QK buffer [S][3072]:
// cols 0..2047 = q heads, 2048..3071 = k heads. grid = (S, 24), block 128.
// ---------------------------------------------------------------------------
__global__ __launch_bounds__(128) void rmsnorm_rope_qk(float* __restrict__ qk,
                                                       const float* __restrict__ cosb,
                                                       const float* __restrict__ sinb) {
  const int s = blockIdx.x;
  const int hh = blockIdx.y;
  const int col = (hh < 16) ? hh * HD : 2048 + (hh - 16) * HD;
  const int t = threadIdx.x;  // 0..127 = d

  float* row = qk + (size_t)s * 3072 + col;
  const float v = row[t];

  __shared__ float sv[HD];
  __shared__ float red[HD];
  sv[t] = v;
  red[t] = v * v;
  __syncthreads();
#pragma unroll
  for (int off = 64; off > 0; off >>= 1) {
    if (t < off) red[t] += red[t + off];
    __syncthreads();
  }
  const float r = rsqrtf(red[0] / (float)HD + EPS);

  const float xn = v * r;
  const float other = sv[t ^ 64] * r;
  const float rot = (t < 64) ? -other : other;
  const float c = cosb[(size_t)s * HD + t];
  const float sn = sinb[(size_t)s * HD + t];
  row[t] = xn * c + rot * sn;
}

// ---------------------------------------------------------------------------
// Flash attention, fp32 VALU, online softmax. q,k from fp32 [S][3072];
// v from bf16 [S][1024]; out bf16 [S][2048]. grid (S/FA_M, NH), block 256.
// ---------------------------------------------------------------------------
#define FA_M 128
#define FA_N 64

__global__ __launch_bounds__(256, 1) void attn_flash_f32(const float* __restrict__ qk,
                                                         const unsigned short* __restrict__ vb,
                                                         unsigned short* __restrict__ out) {
  const int h = blockIdx.y;
  const int kvh = h >> 1;
  const int m0 = blockIdx.x * FA_M;
  const int tid = threadIdx.x;
  const int tx = tid & 15;
  const int ty = tid >> 4;

  const int qcol = h * HD;
  const int kcol = 2048 + kvh * HD;
  const int vcol = kvh * HD;

  __shared__ float Qs[FA_M][HD + 4];
  __shared__ float KVs[FA_N][HD + 4];
  __shared__ float Ps[FA_M][FA_N + 4];

  for (int idx = tid; idx < FA_M * (HD / 4); idx += 256) {
    const int r = idx >> 5;
    const int c4 = (idx & 31) * 4;
    float4 qv = *(const float4*)(qk + (size_t)(m0 + r) * 3072 + qcol + c4);
    qv.x *= QK_SCALE; qv.y *= QK_SCALE; qv.z *= QK_SCALE; qv.w *= QK_SCALE;
    *(float4*)&Qs[r][c4] = qv;
  }

  float m_i[8], l_i[8], O[8][8];
#pragma unroll
  for (int i = 0; i < 8; ++i) {
    m_i[i] = -1e30f;
    l_i[i] = 0.f;
#pragma unroll
    for (int j = 0; j < 8; ++j) O[i][j] = 0.f;
  }

  for (int n0 = 0; n0 < S; n0 += FA_N) {
    __syncthreads();
    for (int idx = tid; idx < FA_N * (HD / 4); idx += 256) {
      const int r = idx >> 5;
      const int c4 = (idx & 31) * 4;
      *(float4*)&KVs[r][c4] =
          *(const float4*)(qk + (size_t)(n0 + r) * 3072 + kcol + c4);
    }
    __syncthreads();

    float s[8][4];
#pragma unroll
    for (int i = 0; i < 8; ++i)
#pragma unroll
      for (int j = 0; j < 4; ++j) s[i][j] = 0.f;

    for (int kk = 0; kk < HD; kk += 4) {
      float a[8][4], b[4][4];
#pragma unroll
      for (int i = 0; i < 8; ++i) {
        const float4 t4 = *(const float4*)&Qs[ty + 16 * i][kk];
        a[i][0] = t4.x; a[i][1] = t4.y; a[i][2] = t4.z; a[i][3] = t4.w;
      }
#pragma unroll
      for (int j = 0; j < 4; ++j) {
        const float4 t4 = *(const float4*)&KVs[tx + 16 * j][kk];
        b[j][0] = t4.x; b[j][1] = t4.y; b[j][2] = t4.z; b[j][3] = t4.w;
      }
#pragma unroll
      for (int i = 0; i < 8; ++i)
#pragma unroll
        for (int j = 0; j < 4; ++j)
#pragma unroll
          for (int t = 0; t < 4; ++t) s[i][j] += a[i][t] * b[j][t];
    }

    float p[8][4];
#pragma unroll
    for (int i = 0; i < 8; ++i) {
      float mt = fmaxf(fmaxf(s[i][0], s[i][1]), fmaxf(s[i][2], s[i][3]));
      mt = fmaxf(mt, __shfl_xor(mt, 1));
      mt = fmaxf(mt, __shfl_xor(mt, 2));
      mt = fmaxf(mt, __shfl_xor(mt, 4));
      mt = fmaxf(mt, __shfl_xor(mt, 8));
      const float mnew = fmaxf(m_i[i], mt);
      const float alpha = __expf(m_i[i] - mnew);
      m_i[i] = mnew;
      float ls = 0.f;
#pragma unroll
      for (int j = 0; j < 4; ++j) {
        p[i][j] = __expf(s[i][j] - mnew);
        ls += p[i][j];
      }
      ls += __shfl_xor(ls, 1);
      ls += __shfl_xor(ls, 2);
      ls += __shfl_xor(ls, 4);
      ls += __shfl_xor(ls, 8);
      l_i[i] = l_i[i] * alpha + ls;
#pragma unroll
      for (int jj = 0; jj < 8; ++jj) O[i][jj] *= alpha;
    }

    __syncthreads();

    // V tile (bf16 -> fp32) over KVs
    for (int idx = tid; idx < FA_N * (HD / 8); idx += 256) {
      const int r = idx >> 4;
      const int c8 = (idx & 15) * 8;
      const s16x8 u = *(const s16x8*)(vb + (size_t)(n0 + r) * 1024 + vcol + c8);
      float4 f0 = make_float4(bf2f((unsigned short)u[0]), bf2f((unsigned short)u[1]),
                              bf2f((unsigned short)u[2]), bf2f((unsigned short)u[3]));
      float4 f1 = make_float4(bf2f((unsigned short)u[4]), bf2f((unsigned short)u[5]),
                              bf2f((unsigned short)u[6]), bf2f((unsigned short)u[7]));
      *(float4*)&KVs[r][c8] = f0;
      *(float4*)&KVs[r][c8 + 4] = f1;
    }
#pragma unroll
    for (int i = 0; i < 8; ++i)
#pragma unroll
      for (int j = 0; j < 4; ++j) Ps[ty + 16 * i][tx + 16 * j] = p[i][j];
    __syncthreads();

    for (int kk = 0; kk < FA_N; kk += 4) {
      float pa[8][4];
#pragma unroll
      for (int i = 0; i < 8; ++i) {
        const float4 t4 = *(const float4*)&Ps[ty + 16 * i][kk];
        pa[i][0] = t4.x; pa[i][1] = t4.y; pa[i][2] = t4.z; pa[i][3] = t4.w;
      }
#pragma unroll
      for (int t = 0; t < 4; ++t) {
        const float4 v0 = *(const float4*)&KVs[kk + t][tx * 8];
        const float4 v1 = *(const float4*)&KVs[kk + t][tx * 8 + 4];
#pragma unroll
        for (int i = 0; i < 8; ++i) {
          const float av = pa[i][t];
          O[i][0] += av * v0.x; O[i][1] += av * v0.y;
          O[i][2] += av * v0.z; O[i][3] += av * v0.w;
          O[i][4] += av * v1.x; O[i][5] += av * v1.y;
          O[i][6] += av * v1.z; O[i][7] += av * v1.w;
        }
      }
    }
  }

#pragma unroll
  for (int i = 0; i < 8; ++i) {
    const float inv = 1.f / l_i[i];
    const int m = m0 + ty + 16 * i;
    s16x8 ov;
#pragma unroll
    for (int j = 0; j < 8; ++j) ov[j] = (short)f2bf(O[i][j] * inv);
    *(s16x8*)(out + (size_t)m * (NH * HD) + h * HD + tx * 8) = ov;
  }
}

// ---------------------------------------------------------------------------
extern "C" void kernel_launch(void* const* d_in, const int* in_sizes, int n_in,
                              void* d_out, int out_size, void* d_ws, size_t ws_size,
                              hipStream_t stream) {
  const float* hidden = (const float*)d_in[0];  // [S][HID]
  const float* cosb   = (const float*)d_in[1];  // [S][HD]
  const float* sinb   = (const float*)d_in[2];  // [S][HD]
  const float* wq     = (const float*)d_in[3];  // [HID][2048]
  const float* wk     = (const float*)d_in[4];  // [HID][1024]
  const float* wv     = (const float*)d_in[5];  // [HID][1024]
  const float* wo     = (const float*)d_in[6];  // [2048][HID]
  float* out = (float*)d_out;                   // [S][HID]

  // Workspace (72 MB total, with reuse after the QK GEMM):
  char* w = (char*)d_ws;
  float* qk_buf            = (float*)(w);                          // 24 MB [S][3072]
  unsigned short* wqkT_hi  = (unsigned short*)(w + (24u << 20));   // 12 MB [3072][2048]
  unsigned short* wqkT_lo  = (unsigned short*)(w + (36u << 20));   // 12 MB
  unsigned short* hid_hi   = (unsigned short*)(w + (48u << 20));   //  8 MB [2048][2048]
  unsigned short* hid_lo   = (unsigned short*)(w + (56u << 20));   //  8 MB
  unsigned short* v_b      = (unsigned short*)(w + (64u << 20));   //  4 MB [2048][1024]
  unsigned short* wvT      = (unsigned short*)(w + (68u << 20));   //  4 MB [1024][2048]
  // reused after QK GEMM (wqkT regions dead):
  unsigned short* woT      = (unsigned short*)(w + (24u << 20));   //  8 MB [2048][2048]
  unsigned short* a_b      = (unsigned short*)(w + (33u << 20));   //  8 MB [2048][2048]

  dim3 blk(256);

  // prologue: splits + transposes
  f32_to_bf16_split<<<dim3((S * HID / 4 + 255) / 256), blk, 0, stream>>>(hidden, hid_hi, hid_lo, S * HID / 4);
  transpose_to_bf16_split<<<dim3(32, 32), blk, 0, stream>>>(wq, wqkT_hi, wqkT_lo, HID, 2048);
  transpose_to_bf16_split<<<dim3(16, 32), blk, 0, stream>>>(wk, wqkT_hi + (size_t)2048 * 2048,
                                                            wqkT_lo + (size_t)2048 * 2048, HID, 1024);
  transpose_to_bf16<<<dim3(16, 32), blk, 0, stream>>>(wv, wvT, 2048, 1024);

  // QK projection, split precision: [2048][2048] x [3072][2048]^T -> fp32 [2048][3072]
  gemm_split_bt<<<dim3(3072 / BN, S / BM), blk, 0, stream>>>(hid_hi, hid_lo, wqkT_hi, wqkT_lo,
                                                             qk_buf, S, 3072, HID, 3072);

  // V projection, plain bf16: -> bf16 [2048][1024]
  gemm_bf16_bt<unsigned short><<<dim3(1024 / BN, S / BM), blk, 0, stream>>>(hid_hi, wvT, v_b, S, 1024, HID, 1024);

  // wo transpose into the now-dead wqkT region
  transpose_to_bf16<<<dim3(32, 32), blk, 0, stream>>>(wo, woT, 2048, HID);

  // RMSNorm + RoPE in place on q,k
  rmsnorm_rope_qk<<<dim3(S, 24), dim3(128), 0, stream>>>(qk_buf, cosb, sinb);

  // attention -> bf16 [2048][2048]
  attn_flash_f32<<<dim3(S / FA_M, NH), blk, 0, stream>>>(qk_buf, v_b, a_b);

  // output projection, plain bf16 -> fp32 out
  gemm_bf16_bt<float><<<dim3(HID / BN, S / BM), blk, 0, stream>>>(a_b, woT, out, S, HID, 2048, HID);
}

// Round 5
// 535.508 us; speedup vs baseline: 17.7264x; 1.6915x over previous
//
#include <hip/hip_runtime.h>
#include <hip/hip_bf16.h>
#include <math.h>

// Problem constants
#define S 2048
#define HID 2048
#define NH 16
#define KVH 8
#define HD 128
#define EPS 1e-6f
#define QK_SCALE 11.313708498984760390f  // 1/SCALING = sqrt(128)

typedef __attribute__((ext_vector_type(8))) short s16x8;
typedef __attribute__((ext_vector_type(4))) float f32x4;

__device__ __forceinline__ unsigned short f2bf(float f) {
  __hip_bfloat16 h = __float2bfloat16(f);
  return *(unsigned short*)&h;
}
__device__ __forceinline__ float bf2f(unsigned short u) {
  unsigned int x = ((unsigned int)u) << 16;
  return __builtin_bit_cast(float, x);
}

__device__ __forceinline__ void gload16(const void* g, void* l) {
  __builtin_amdgcn_global_load_lds(
      (const __attribute__((address_space(1))) void*)g,
      (__attribute__((address_space(3))) void*)l, 16, 0, 0);
}

// ---------------------------------------------------------------------------
// fp32 -> split bf16 (hi + lo) elementwise.
// ---------------------------------------------------------------------------
__global__ __launch_bounds__(256) void f32_to_bf16_split(const float* __restrict__ in,
                                                         unsigned short* __restrict__ hi,
                                                         unsigned short* __restrict__ lo,
                                                         int n4) {
  const int i = blockIdx.x * 256 + threadIdx.x;
  if (i < n4) {
    const float4 v = *(const float4*)(in + (size_t)i * 4);
    ushort4 h, l;
    h.x = f2bf(v.x); l.x = f2bf(v.x - bf2f(h.x));
    h.y = f2bf(v.y); l.y = f2bf(v.y - bf2f(h.y));
    h.z = f2bf(v.z); l.z = f2bf(v.z - bf2f(h.z));
    h.w = f2bf(v.w); l.w = f2bf(v.w - bf2f(h.w));
    *(ushort4*)(hi + (size_t)i * 4) = h;
    *(ushort4*)(lo + (size_t)i * 4) = l;
  }
}

// ---------------------------------------------------------------------------
// Transpose fp32 [K][N] -> bf16 [N][K], plain.
// ---------------------------------------------------------------------------
__global__ __launch_bounds__(256) void transpose_to_bf16(const float* __restrict__ in,
                                                         unsigned short* __restrict__ out,
                                                         int K, int N) {
  __shared__ float t[64][65];
  const int n0 = blockIdx.x * 64;
  const int k0 = blockIdx.y * 64;
  const int tid = threadIdx.x;

  for (int idx = tid; idx < 64 * 16; idx += 256) {
    const int r = idx >> 4;
    const int c4 = (idx & 15) * 4;
    const float4 v = *(const float4*)(in + (size_t)(k0 + r) * N + n0 + c4);
    t[r][c4 + 0] = v.x; t[r][c4 + 1] = v.y; t[r][c4 + 2] = v.z; t[r][c4 + 3] = v.w;
  }
  __syncthreads();
  for (int idx = tid; idx < 64 * 16; idx += 256) {
    const int a = idx >> 4;
    const int b4 = (idx & 15) * 4;
    ushort4 u;
    u.x = f2bf(t[b4 + 0][a]); u.y = f2bf(t[b4 + 1][a]);
    u.z = f2bf(t[b4 + 2][a]); u.w = f2bf(t[b4 + 3][a]);
    *(ushort4*)(out + (size_t)(n0 + a) * K + k0 + b4) = u;
  }
}

// ---------------------------------------------------------------------------
// Transpose fp32 [K][N] -> split bf16 hi/lo [N][K].
// ---------------------------------------------------------------------------
__global__ __launch_bounds__(256) void transpose_to_bf16_split(const float* __restrict__ in,
                                                               unsigned short* __restrict__ ohi,
                                                               unsigned short* __restrict__ olo,
                                                               int K, int N) {
  __shared__ float t[64][65];
  const int n0 = blockIdx.x * 64;
  const int k0 = blockIdx.y * 64;
  const int tid = threadIdx.x;

  for (int idx = tid; idx < 64 * 16; idx += 256) {
    const int r = idx >> 4;
    const int c4 = (idx & 15) * 4;
    const float4 v = *(const float4*)(in + (size_t)(k0 + r) * N + n0 + c4);
    t[r][c4 + 0] = v.x; t[r][c4 + 1] = v.y; t[r][c4 + 2] = v.z; t[r][c4 + 3] = v.w;
  }
  __syncthreads();
  for (int idx = tid; idx < 64 * 16; idx += 256) {
    const int a = idx >> 4;
    const int b4 = (idx & 15) * 4;
    ushort4 h, l;
#pragma unroll
    for (int q = 0; q < 4; ++q) {
      const float v = t[b4 + q][a];
      const unsigned short hu = f2bf(v);
      const unsigned short lu = f2bf(v - bf2f(hu));
      ((unsigned short*)&h)[q] = hu;
      ((unsigned short*)&l)[q] = lu;
    }
    *(ushort4*)(ohi + (size_t)(n0 + a) * K + k0 + b4) = h;
    *(ushort4*)(olo + (size_t)(n0 + a) * K + k0 + b4) = l;
  }
}

// ---------------------------------------------------------------------------
// Plain bf16 MFMA GEMM (m97 structure): C[M][ldc] = A[M][K] * Bt[N][K]^T.
// ---------------------------------------------------------------------------
#define BM 128
#define BN 128
#define BK 32

template <typename OT>
__global__ __launch_bounds__(256) void gemm_bf16_bt(const unsigned short* __restrict__ A,
                                                    const unsigned short* __restrict__ Bt,
                                                    OT* __restrict__ C,
                                                    int M, int N, int K, int ldc) {
  __shared__ unsigned short As[BM * BK];
  __shared__ unsigned short Bs[BN * BK];

  const int tid = threadIdx.x;
  const int lane = tid & 63;
  const int wave = tid >> 6;
  const int m0 = blockIdx.y * BM;
  const int n0 = blockIdx.x * BN;

  const int qm = (wave >> 1) * 64;
  const int qn = (wave & 1) * 64;
  const int l15 = lane & 15;
  const int quad = lane >> 4;

  const int st_row = lane >> 2;
  const int st_col = (lane & 3) * 8;

  f32x4 acc[4][4] = {};

  for (int k0 = 0; k0 < K; k0 += BK) {
#pragma unroll
    for (int p = 0; p < 2; ++p) {
      const int rb = p * 64 + wave * 16;
      gload16(A + (size_t)(m0 + rb + st_row) * K + k0 + st_col, &As[rb * BK]);
      gload16(Bt + (size_t)(n0 + rb + st_row) * K + k0 + st_col, &Bs[rb * BK]);
    }
    __syncthreads();

    s16x8 a[4], b[4];
#pragma unroll
    for (int i = 0; i < 4; ++i)
      a[i] = *(const s16x8*)&As[(qm + i * 16 + l15) * BK + quad * 8];
#pragma unroll
    for (int j = 0; j < 4; ++j)
      b[j] = *(const s16x8*)&Bs[(qn + j * 16 + l15) * BK + quad * 8];
#pragma unroll
    for (int i = 0; i < 4; ++i)
#pragma unroll
      for (int j = 0; j < 4; ++j)
        acc[i][j] = __builtin_amdgcn_mfma_f32_16x16x32_bf16(a[i], b[j], acc[i][j], 0, 0, 0);
    __syncthreads();
  }

#pragma unroll
  for (int i = 0; i < 4; ++i) {
    const int row_base = m0 + qm + i * 16 + quad * 4;
#pragma unroll
    for (int j = 0; j < 4; ++j) {
      const int col = n0 + qn + j * 16 + l15;
#pragma unroll
      for (int r = 0; r < 4; ++r) {
        if constexpr (sizeof(OT) == 2)
          C[(size_t)(row_base + r) * ldc + col] = (OT)f2bf(acc[i][j][r]);
        else
          C[(size_t)(row_base + r) * ldc + col] = acc[i][j][r];
      }
    }
  }
}

// ---------------------------------------------------------------------------
// bf16 MFMA GEMM with TRANSPOSED bf16 store: Ct[N][ldct] = (A * Bt^T)^T.
// Used for the V projection so attention can read V in B-operand layout.
// ---------------------------------------------------------------------------
__global__ __launch_bounds__(256) void gemm_bf16_bt_vt(const unsigned short* __restrict__ A,
                                                       const unsigned short* __restrict__ Bt,
                                                       unsigned short* __restrict__ Ct,
                                                       int M, int N, int K, int ldct) {
  __shared__ unsigned short As[BM * BK];
  __shared__ unsigned short Bs[BN * BK];

  const int tid = threadIdx.x;
  const int lane = tid & 63;
  const int wave = tid >> 6;
  const int m0 = blockIdx.y * BM;
  const int n0 = blockIdx.x * BN;

  const int qm = (wave >> 1) * 64;
  const int qn = (wave & 1) * 64;
  const int l15 = lane & 15;
  const int quad = lane >> 4;

  const int st_row = lane >> 2;
  const int st_col = (lane & 3) * 8;

  f32x4 acc[4][4] = {};

  for (int k0 = 0; k0 < K; k0 += BK) {
#pragma unroll
    for (int p = 0; p < 2; ++p) {
      const int rb = p * 64 + wave * 16;
      gload16(A + (size_t)(m0 + rb + st_row) * K + k0 + st_col, &As[rb * BK]);
      gload16(Bt + (size_t)(n0 + rb + st_row) * K + k0 + st_col, &Bs[rb * BK]);
    }
    __syncthreads();

    s16x8 a[4], b[4];
#pragma unroll
    for (int i = 0; i < 4; ++i)
      a[i] = *(const s16x8*)&As[(qm + i * 16 + l15) * BK + quad * 8];
#pragma unroll
    for (int j = 0; j < 4; ++j)
      b[j] = *(const s16x8*)&Bs[(qn + j * 16 + l15) * BK + quad * 8];
#pragma unroll
    for (int i = 0; i < 4; ++i)
#pragma unroll
      for (int j = 0; j < 4; ++j)
        acc[i][j] = __builtin_amdgcn_mfma_f32_16x16x32_bf16(a[i], b[j], acc[i][j], 0, 0, 0);
    __syncthreads();
  }

  // transposed store: Ct[n][m], 4 consecutive m per lane -> 8B bf16 store
#pragma unroll
  for (int i = 0; i < 4; ++i) {
    const int row_base = m0 + qm + i * 16 + quad * 4;  // m
#pragma unroll
    for (int j = 0; j < 4; ++j) {
      const int col = n0 + qn + j * 16 + l15;          // n
      ushort4 u;
      u.x = f2bf(acc[i][j][0]); u.y = f2bf(acc[i][j][1]);
      u.z = f2bf(acc[i][j][2]); u.w = f2bf(acc[i][j][3]);
      *(ushort4*)(Ct + (size_t)col * ldct + row_base) = u;
    }
  }
}

// ---------------------------------------------------------------------------
// Split-precision bf16 MFMA GEMM: C = (Ahi+Alo) * (Bhi+Blo)^T, dropping lo*lo.
// ---------------------------------------------------------------------------
__global__ __launch_bounds__(256) void gemm_split_bt(const unsigned short* __restrict__ Ahi,
                                                     const unsigned short* __restrict__ Alo,
                                                     const unsigned short* __restrict__ Bhi,
                                                     const unsigned short* __restrict__ Blo,
                                                     float* __restrict__ C,
                                                     int M, int N, int K, int ldc) {
  __shared__ unsigned short AsH[BM * BK];
  __shared__ unsigned short AsL[BM * BK];
  __shared__ unsigned short BsH[BN * BK];
  __shared__ unsigned short BsL[BN * BK];

  const int tid = threadIdx.x;
  const int lane = tid & 63;
  const int wave = tid >> 6;
  const int m0 = blockIdx.y * BM;
  const int n0 = blockIdx.x * BN;

  const int qm = (wave >> 1) * 64;
  const int qn = (wave & 1) * 64;
  const int l15 = lane & 15;
  const int quad = lane >> 4;

  const int st_row = lane >> 2;
  const int st_col = (lane & 3) * 8;

  f32x4 acc[4][4] = {};

  for (int k0 = 0; k0 < K; k0 += BK) {
#pragma unroll
    for (int p = 0; p < 2; ++p) {
      const int rb = p * 64 + wave * 16;
      const size_t aoff = (size_t)(m0 + rb + st_row) * K + k0 + st_col;
      const size_t boff = (size_t)(n0 + rb + st_row) * K + k0 + st_col;
      gload16(Ahi + aoff, &AsH[rb * BK]);
      gload16(Alo + aoff, &AsL[rb * BK]);
      gload16(Bhi + boff, &BsH[rb * BK]);
      gload16(Blo + boff, &BsL[rb * BK]);
    }
    __syncthreads();

    s16x8 ah[4], al[4], bh[4], bl[4];
#pragma unroll
    for (int i = 0; i < 4; ++i) {
      const int ro = (qm + i * 16 + l15) * BK + quad * 8;
      ah[i] = *(const s16x8*)&AsH[ro];
      al[i] = *(const s16x8*)&AsL[ro];
    }
#pragma unroll
    for (int j = 0; j < 4; ++j) {
      const int ro = (qn + j * 16 + l15) * BK + quad * 8;
      bh[j] = *(const s16x8*)&BsH[ro];
      bl[j] = *(const s16x8*)&BsL[ro];
    }
#pragma unroll
    for (int i = 0; i < 4; ++i)
#pragma unroll
      for (int j = 0; j < 4; ++j) {
        acc[i][j] = __builtin_amdgcn_mfma_f32_16x16x32_bf16(ah[i], bh[j], acc[i][j], 0, 0, 0);
        acc[i][j] = __builtin_amdgcn_mfma_f32_16x16x32_bf16(ah[i], bl[j], acc[i][j], 0, 0, 0);
        acc[i][j] = __builtin_amdgcn_mfma_f32_16x16x32_bf16(al[i], bh[j], acc[i][j], 0, 0, 0);
      }
    __syncthreads();
  }

#pragma unroll
  for (int i = 0; i < 4; ++i) {
    const int row_base = m0 + qm + i * 16 + quad * 4;
#pragma unroll
    for (int j = 0; j < 4; ++j) {
      const int col = n0 + qn + j * 16 + l15;
#pragma unroll
      for (int r = 0; r < 4; ++r)
        C[(size_t)(row_base + r) * ldc + col] = acc[i][j][r];
    }
  }
}

// ---------------------------------------------------------------------------
// Fused RMSNorm + RoPE on packed fp32 QK [S][3072], emitting SPLIT bf16:
// q (pre-scaled by QK_SCALE) -> qh/ql [S][2048]; k -> kh/kl [S][1024].
// grid (S, 24), block 128.
// ---------------------------------------------------------------------------
__global__ __launch_bounds__(128) void rmsnorm_rope_split(const float* __restrict__ qk,
                                                          const float* __restrict__ cosb,
                                                          const float* __restrict__ sinb,
                                                          unsigned short* __restrict__ qh,
                                                          unsigned short* __restrict__ ql,
                                                          unsigned short* __restrict__ kh,
                                                          unsigned short* __restrict__ kl) {
  const int s = blockIdx.x;
  const int hh = blockIdx.y;
  const bool is_q = (hh < 16);
  const int col = is_q ? hh * HD : 2048 + (hh - 16) * HD;
  const int t = threadIdx.x;  // 0..127 = d

  const float* row = qk + (size_t)s * 3072 + col;
  const float v = row[t];

  __shared__ float sv[HD];
  __shared__ float red[HD];
  sv[t] = v;
  red[t] = v * v;
  __syncthreads();
#pragma unroll
  for (int off = 64; off > 0; off >>= 1) {
    if (t < off) red[t] += red[t + off];
    __syncthreads();
  }
  const float r = rsqrtf(red[0] / (float)HD + EPS);

  const float xn = v * r;
  const float other = sv[t ^ 64] * r;
  const float rot = (t < 64) ? -other : other;
  const float c = cosb[(size_t)s * HD + t];
  const float sn = sinb[(size_t)s * HD + t];
  float o = xn * c + rot * sn;
  if (is_q) o *= QK_SCALE;

  const unsigned short hu = f2bf(o);
  const unsigned short lu = f2bf(o - bf2f(hu));
  if (is_q) {
    qh[(size_t)s * 2048 + hh * HD + t] = hu;
    ql[(size_t)s * 2048 + hh * HD + t] = lu;
  } else {
    kh[(size_t)s * 1024 + (hh - 16) * HD + t] = hu;
    kl[(size_t)s * 1024 + (hh - 16) * HD + t] = lu;
  }
}

// ---------------------------------------------------------------------------
// Flash attention, MFMA. grid (S/128, NH), block 256 (4 waves x 32 Q-rows).
// QK^T: split bf16 (3 MFMAs) for fp32-grade scores; PV: plain bf16.
// q pre-scaled. vt is V transposed [KVH*HD][S] so V stages straight into
// B-operand layout. P round-trips through LDS (C-layout -> A-layout).
// LDS ~138 KB -> 1 block/CU.
// ---------------------------------------------------------------------------
#define FA_N 64

__global__ __launch_bounds__(256, 1) void attn_flash_mfma(const unsigned short* __restrict__ qh,
                                                          const unsigned short* __restrict__ ql,
                                                          const unsigned short* __restrict__ kh,
                                                          const unsigned short* __restrict__ kl,
                                                          const unsigned short* __restrict__ vt,
                                                          unsigned short* __restrict__ out) {
  const int h = blockIdx.y;
  const int kvh = h >> 1;
  const int m0 = blockIdx.x * 128;
  const int tid = threadIdx.x;
  const int lane = tid & 63;
  const int wave = tid >> 6;
  const int l15 = lane & 15;
  const int quad = lane >> 4;

  __shared__ unsigned short Qh[128][136];  // [qrow][d], +8 pad (2-way banks)
  __shared__ unsigned short Ql[128][136];
  __shared__ unsigned short Kh[64][136];   // [key][d]
  __shared__ unsigned short Kl[64][136];
  __shared__ unsigned short Vt[128][72];   // [d][key]
  __shared__ unsigned short Pt[128][72];   // [qrow][key]

  // ---- stage Q hi/lo (once) ----
  for (int idx = tid; idx < 128 * 16; idx += 256) {
    const int r = idx >> 4;
    const int c = (idx & 15) * 8;
    *(s16x8*)&Qh[r][c] = *(const s16x8*)(qh + (size_t)(m0 + r) * 2048 + h * HD + c);
    *(s16x8*)&Ql[r][c] = *(const s16x8*)(ql + (size_t)(m0 + r) * 2048 + h * HD + c);
  }

  f32x4 O[2][8] = {};
  float m_i[2][4], l_i[2][4];
#pragma unroll
  for (int i = 0; i < 2; ++i)
#pragma unroll
    for (int r = 0; r < 4; ++r) { m_i[i][r] = -1e30f; l_i[i][r] = 0.f; }

  for (int n0 = 0; n0 < S; n0 += FA_N) {
    __syncthreads();  // protect Kh/Kl/Vt from previous iteration's readers
    // ---- stage K hi/lo + Vt ----
    for (int idx = tid; idx < 64 * 16; idx += 256) {
      const int r = idx >> 4;
      const int c = (idx & 15) * 8;
      *(s16x8*)&Kh[r][c] = *(const s16x8*)(kh + (size_t)(n0 + r) * 1024 + kvh * HD + c);
      *(s16x8*)&Kl[r][c] = *(const s16x8*)(kl + (size_t)(n0 + r) * 1024 + kvh * HD + c);
    }
    for (int idx = tid; idx < 128 * 8; idx += 256) {
      const int r = idx >> 3;
      const int c = (idx & 7) * 8;
      *(s16x8*)&Vt[r][c] = *(const s16x8*)(vt + (size_t)(kvh * HD + r) * 2048 + n0 + c);
    }
    __syncthreads();

    // ---- S = Q K^T, split precision (rows wave*32+i*16+l15, cols j*16+l15) ----
    f32x4 sacc[2][4] = {};
#pragma unroll
    for (int ks = 0; ks < 4; ++ks) {
      s16x8 ah[2], al[2], bh[4], bl[4];
#pragma unroll
      for (int i = 0; i < 2; ++i) {
        ah[i] = *(const s16x8*)&Qh[wave * 32 + i * 16 + l15][ks * 32 + quad * 8];
        al[i] = *(const s16x8*)&Ql[wave * 32 + i * 16 + l15][ks * 32 + quad * 8];
      }
#pragma unroll
      for (int j = 0; j < 4; ++j) {
        bh[j] = *(const s16x8*)&Kh[j * 16 + l15][ks * 32 + quad * 8];
        bl[j] = *(const s16x8*)&Kl[j * 16 + l15][ks * 32 + quad * 8];
      }
#pragma unroll
      for (int i = 0; i < 2; ++i)
#pragma unroll
        for (int j = 0; j < 4; ++j) {
          sacc[i][j] = __builtin_amdgcn_mfma_f32_16x16x32_bf16(ah[i], bh[j], sacc[i][j], 0, 0, 0);
          sacc[i][j] = __builtin_amdgcn_mfma_f32_16x16x32_bf16(ah[i], bl[j], sacc[i][j], 0, 0, 0);
          sacc[i][j] = __builtin_amdgcn_mfma_f32_16x16x32_bf16(al[i], bh[j], sacc[i][j], 0, 0, 0);
        }
    }

    // ---- online softmax; C-layout row = quad*4+r, col = l15+16j ----
#pragma unroll
    for (int i = 0; i < 2; ++i) {
#pragma unroll
      for (int r = 0; r < 4; ++r) {
        float mt = fmaxf(fmaxf(sacc[i][0][r], sacc[i][1][r]),
                         fmaxf(sacc[i][2][r], sacc[i][3][r]));
        mt = fmaxf(mt, __shfl_xor(mt, 1));
        mt = fmaxf(mt, __shfl_xor(mt, 2));
        mt = fmaxf(mt, __shfl_xor(mt, 4));
        mt = fmaxf(mt, __shfl_xor(mt, 8));
        const float mnew = fmaxf(m_i[i][r], mt);
        const float alpha = __expf(m_i[i][r] - mnew);
        m_i[i][r] = mnew;
        float p0 = __expf(sacc[i][0][r] - mnew);
        float p1 = __expf(sacc[i][1][r] - mnew);
        float p2 = __expf(sacc[i][2][r] - mnew);
        float p3 = __expf(sacc[i][3][r] - mnew);
        float ls = p0 + p1 + p2 + p3;
        ls += __shfl_xor(ls, 1);
        ls += __shfl_xor(ls, 2);
        ls += __shfl_xor(ls, 4);
        ls += __shfl_xor(ls, 8);
        l_i[i][r] = l_i[i][r] * alpha + ls;
#pragma unroll
        for (int jd = 0; jd < 8; ++jd) O[i][jd][r] *= alpha;
        const int prow = wave * 32 + i * 16 + quad * 4 + r;
        Pt[prow][l15 + 0]  = f2bf(p0);
        Pt[prow][l15 + 16] = f2bf(p1);
        Pt[prow][l15 + 32] = f2bf(p2);
        Pt[prow][l15 + 48] = f2bf(p3);
      }
    }
    __syncthreads();  // Pt visible (cheap insurance; also keeps Vt coherent)

    // ---- O += P V ----
#pragma unroll
    for (int ks2 = 0; ks2 < 2; ++ks2) {
      s16x8 pa[2], vb[8];
#pragma unroll
      for (int i = 0; i < 2; ++i)
        pa[i] = *(const s16x8*)&Pt[wave * 32 + i * 16 + l15][ks2 * 32 + quad * 8];
#pragma unroll
      for (int jd = 0; jd < 8; ++jd)
        vb[jd] = *(const s16x8*)&Vt[jd * 16 + l15][ks2 * 32 + quad * 8];
#pragma unroll
      for (int i = 0; i < 2; ++i)
#pragma unroll
        for (int jd = 0; jd < 8; ++jd)
          O[i][jd] = __builtin_amdgcn_mfma_f32_16x16x32_bf16(pa[i], vb[jd], O[i][jd], 0, 0, 0);
    }
  }

  // ---- epilogue: normalize, bf16 store ----
#pragma unroll
  for (int i = 0; i < 2; ++i) {
#pragma unroll
    for (int r = 0; r < 4; ++r) {
      const float inv = 1.f / l_i[i][r];
      const int row = m0 + wave * 32 + i * 16 + quad * 4 + r;
#pragma unroll
      for (int jd = 0; jd < 8; ++jd)
        out[(size_t)row * 2048 + h * HD + jd * 16 + l15] = f2bf(O[i][jd][r] * inv);
    }
  }
}

// ---------------------------------------------------------------------------
extern "C" void kernel_launch(void* const* d_in, const int* in_sizes, int n_in,
                              void* d_out, int out_size, void* d_ws, size_t ws_size,
                              hipStream_t stream) {
  const float* hidden = (const float*)d_in[0];  // [S][HID]
  const float* cosb   = (const float*)d_in[1];  // [S][HD]
  const float* sinb   = (const float*)d_in[2];  // [S][HD]
  const float* wq     = (const float*)d_in[3];  // [HID][2048]
  const float* wk     = (const float*)d_in[4];  // [HID][1024]
  const float* wv     = (const float*)d_in[5];  // [HID][1024]
  const float* wo     = (const float*)d_in[6];  // [2048][HID]
  float* out = (float*)d_out;                   // [S][HID]

  // Workspace map (72 MB, regions reused once dead):
  char* w = (char*)d_ws;
  float* qk_buf           = (float*)(w);                          //  0-24 MB fp32 [S][3072]
  unsigned short* wqkT_hi = (unsigned short*)(w + (24u << 20));   // 24-36 (dead after QK gemm)
  unsigned short* wqkT_lo = (unsigned short*)(w + (36u << 20));   // 36-48 (dead after QK gemm)
  unsigned short* hid_hi  = (unsigned short*)(w + (48u << 20));   // 48-56 (dead after V gemm)
  unsigned short* hid_lo  = (unsigned short*)(w + (56u << 20));   // 56-64 (dead after QK gemm)
  unsigned short* vt_b    = (unsigned short*)(w + (64u << 20));   // 64-68 V^T bf16 [1024][2048]
  unsigned short* wvT     = (unsigned short*)(w + (68u << 20));   // 68-72
  // reuse after QK gemm:
  unsigned short* q_hi    = (unsigned short*)(w + (24u << 20));   // 24-32 [S][2048]
  unsigned short* q_lo    = (unsigned short*)(w + (32u << 20));   // 32-40
  unsigned short* k_hi    = (unsigned short*)(w + (40u << 20));   // 40-44 [S][1024]
  unsigned short* k_lo    = (unsigned short*)(w + (44u << 20));   // 44-48
  // reuse after V gemm:
  unsigned short* woT     = (unsigned short*)(w + (48u << 20));   // 48-56 [2048][2048]
  unsigned short* a_b     = (unsigned short*)(w + (56u << 20));   // 56-64 [S][2048]

  dim3 blk(256);

  // prologue
  f32_to_bf16_split<<<dim3((S * HID / 4 + 255) / 256), blk, 0, stream>>>(hidden, hid_hi, hid_lo, S * HID / 4);
  transpose_to_bf16_split<<<dim3(32, 32), blk, 0, stream>>>(wq, wqkT_hi, wqkT_lo, HID, 2048);
  transpose_to_bf16_split<<<dim3(16, 32), blk, 0, stream>>>(wk, wqkT_hi + (size_t)2048 * 2048,
                                                            wqkT_lo + (size_t)2048 * 2048, HID, 1024);
  transpose_to_bf16<<<dim3(16, 32), blk, 0, stream>>>(wv, wvT, 2048, 1024);

  // QK projection (split precision) -> fp32 [S][3072]
  gemm_split_bt<<<dim3(3072 / BN, S / BM), blk, 0, stream>>>(hid_hi, hid_lo, wqkT_hi, wqkT_lo,
                                                             qk_buf, S, 3072, HID, 3072);

  // V projection -> transposed bf16 [1024][2048]
  gemm_bf16_bt_vt<<<dim3(1024 / BN, S / BM), blk, 0, stream>>>(hid_hi, wvT, vt_b, S, 1024, HID, 2048);

  // wo transpose into dead hid_hi region (after V gemm in stream order)
  transpose_to_bf16<<<dim3(32, 32), blk, 0, stream>>>(wo, woT, 2048, HID);

  // RMSNorm + RoPE -> split bf16 q/k (q pre-scaled)
  rmsnorm_rope_split<<<dim3(S, 24), dim3(128), 0, stream>>>(qk_buf, cosb, sinb, q_hi, q_lo, k_hi, k_lo);

  // MFMA flash attention -> bf16 [S][2048]
  attn_flash_mfma<<<dim3(S / 128, NH), blk, 0, stream>>>(q_hi, q_lo, k_hi, k_lo, vt_b, a_b);

  // output projection -> fp32 out
  gemm_bf16_bt<float><<<dim3(HID / BN, S / BM), blk, 0, stream>>>(a_b, woT, out, S, HID, 2048, HID);
}

// Round 6
// 489.385 us; speedup vs baseline: 19.3971x; 1.0942x over previous
//
#include <hip/hip_runtime.h>
#include <hip/hip_bf16.h>
#include <math.h>

// Problem constants
#define S 2048
#define HID 2048
#define NH 16
#define KVH 8
#define HD 128
#define EPS 1e-6f
#define QK_SCALE 11.313708498984760390f  // 1/SCALING = sqrt(128)

typedef __attribute__((ext_vector_type(8))) short s16x8;
typedef __attribute__((ext_vector_type(4))) float f32x4;

__device__ __forceinline__ unsigned short f2bf(float f) {
  __hip_bfloat16 h = __float2bfloat16(f);
  return *(unsigned short*)&h;
}
__device__ __forceinline__ float bf2f(unsigned short u) {
  unsigned int x = ((unsigned int)u) << 16;
  return __builtin_bit_cast(float, x);
}

__device__ __forceinline__ void gload16(const void* g, void* l) {
  __builtin_amdgcn_global_load_lds(
      (const __attribute__((address_space(1))) void*)g,
      (__attribute__((address_space(3))) void*)l, 16, 0, 0);
}

// ---------------------------------------------------------------------------
// fp32 -> split bf16 (hi + lo) elementwise.
// ---------------------------------------------------------------------------
__global__ __launch_bounds__(256) void f32_to_bf16_split(const float* __restrict__ in,
                                                         unsigned short* __restrict__ hi,
                                                         unsigned short* __restrict__ lo,
                                                         int n4) {
  const int i = blockIdx.x * 256 + threadIdx.x;
  if (i < n4) {
    const float4 v = *(const float4*)(in + (size_t)i * 4);
    ushort4 h, l;
    h.x = f2bf(v.x); l.x = f2bf(v.x - bf2f(h.x));
    h.y = f2bf(v.y); l.y = f2bf(v.y - bf2f(h.y));
    h.z = f2bf(v.z); l.z = f2bf(v.z - bf2f(h.z));
    h.w = f2bf(v.w); l.w = f2bf(v.w - bf2f(h.w));
    *(ushort4*)(hi + (size_t)i * 4) = h;
    *(ushort4*)(lo + (size_t)i * 4) = l;
  }
}

// ---------------------------------------------------------------------------
// Transpose fp32 [K][N] -> bf16 [N][K], plain.
// ---------------------------------------------------------------------------
__global__ __launch_bounds__(256) void transpose_to_bf16(const float* __restrict__ in,
                                                         unsigned short* __restrict__ out,
                                                         int K, int N) {
  __shared__ float t[64][65];
  const int n0 = blockIdx.x * 64;
  const int k0 = blockIdx.y * 64;
  const int tid = threadIdx.x;

  for (int idx = tid; idx < 64 * 16; idx += 256) {
    const int r = idx >> 4;
    const int c4 = (idx & 15) * 4;
    const float4 v = *(const float4*)(in + (size_t)(k0 + r) * N + n0 + c4);
    t[r][c4 + 0] = v.x; t[r][c4 + 1] = v.y; t[r][c4 + 2] = v.z; t[r][c4 + 3] = v.w;
  }
  __syncthreads();
  for (int idx = tid; idx < 64 * 16; idx += 256) {
    const int a = idx >> 4;
    const int b4 = (idx & 15) * 4;
    ushort4 u;
    u.x = f2bf(t[b4 + 0][a]); u.y = f2bf(t[b4 + 1][a]);
    u.z = f2bf(t[b4 + 2][a]); u.w = f2bf(t[b4 + 3][a]);
    *(ushort4*)(out + (size_t)(n0 + a) * K + k0 + b4) = u;
  }
}

// ---------------------------------------------------------------------------
// Transpose fp32 [K][N] -> split bf16 hi/lo [N][K].
// ---------------------------------------------------------------------------
__global__ __launch_bounds__(256) void transpose_to_bf16_split(const float* __restrict__ in,
                                                               unsigned short* __restrict__ ohi,
                                                               unsigned short* __restrict__ olo,
                                                               int K, int N) {
  __shared__ float t[64][65];
  const int n0 = blockIdx.x * 64;
  const int k0 = blockIdx.y * 64;
  const int tid = threadIdx.x;

  for (int idx = tid; idx < 64 * 16; idx += 256) {
    const int r = idx >> 4;
    const int c4 = (idx & 15) * 4;
    const float4 v = *(const float4*)(in + (size_t)(k0 + r) * N + n0 + c4);
    t[r][c4 + 0] = v.x; t[r][c4 + 1] = v.y; t[r][c4 + 2] = v.z; t[r][c4 + 3] = v.w;
  }
  __syncthreads();
  for (int idx = tid; idx < 64 * 16; idx += 256) {
    const int a = idx >> 4;
    const int b4 = (idx & 15) * 4;
    ushort4 h, l;
#pragma unroll
    for (int q = 0; q < 4; ++q) {
      const float v = t[b4 + q][a];
      const unsigned short hu = f2bf(v);
      const unsigned short lu = f2bf(v - bf2f(hu));
      ((unsigned short*)&h)[q] = hu;
      ((unsigned short*)&l)[q] = lu;
    }
    *(ushort4*)(ohi + (size_t)(n0 + a) * K + k0 + b4) = h;
    *(ushort4*)(olo + (size_t)(n0 + a) * K + k0 + b4) = l;
  }
}

// ---------------------------------------------------------------------------
// Plain bf16 MFMA GEMM (m97 structure): C[M][ldc] = A[M][K] * Bt[N][K]^T.
// ---------------------------------------------------------------------------
#define BM 128
#define BN 128
#define BK 32

template <typename OT>
__global__ __launch_bounds__(256) void gemm_bf16_bt(const unsigned short* __restrict__ A,
                                                    const unsigned short* __restrict__ Bt,
                                                    OT* __restrict__ C,
                                                    int M, int N, int K, int ldc) {
  __shared__ unsigned short As[BM * BK];
  __shared__ unsigned short Bs[BN * BK];

  const int tid = threadIdx.x;
  const int lane = tid & 63;
  const int wave = tid >> 6;
  const int m0 = blockIdx.y * BM;
  const int n0 = blockIdx.x * BN;

  const int qm = (wave >> 1) * 64;
  const int qn = (wave & 1) * 64;
  const int l15 = lane & 15;
  const int quad = lane >> 4;

  const int st_row = lane >> 2;
  const int st_col = (lane & 3) * 8;

  f32x4 acc[4][4] = {};

  for (int k0 = 0; k0 < K; k0 += BK) {
#pragma unroll
    for (int p = 0; p < 2; ++p) {
      const int rb = p * 64 + wave * 16;
      gload16(A + (size_t)(m0 + rb + st_row) * K + k0 + st_col, &As[rb * BK]);
      gload16(Bt + (size_t)(n0 + rb + st_row) * K + k0 + st_col, &Bs[rb * BK]);
    }
    __syncthreads();

    s16x8 a[4], b[4];
#pragma unroll
    for (int i = 0; i < 4; ++i)
      a[i] = *(const s16x8*)&As[(qm + i * 16 + l15) * BK + quad * 8];
#pragma unroll
    for (int j = 0; j < 4; ++j)
      b[j] = *(const s16x8*)&Bs[(qn + j * 16 + l15) * BK + quad * 8];
#pragma unroll
    for (int i = 0; i < 4; ++i)
#pragma unroll
      for (int j = 0; j < 4; ++j)
        acc[i][j] = __builtin_amdgcn_mfma_f32_16x16x32_bf16(a[i], b[j], acc[i][j], 0, 0, 0);
    __syncthreads();
  }

#pragma unroll
  for (int i = 0; i < 4; ++i) {
    const int row_base = m0 + qm + i * 16 + quad * 4;
#pragma unroll
    for (int j = 0; j < 4; ++j) {
      const int col = n0 + qn + j * 16 + l15;
#pragma unroll
      for (int r = 0; r < 4; ++r) {
        if constexpr (sizeof(OT) == 2)
          C[(size_t)(row_base + r) * ldc + col] = (OT)f2bf(acc[i][j][r]);
        else
          C[(size_t)(row_base + r) * ldc + col] = acc[i][j][r];
      }
    }
  }
}

// ---------------------------------------------------------------------------
// bf16 MFMA GEMM with TRANSPOSED bf16 store: Ct[N][ldct] = (A * Bt^T)^T.
// ---------------------------------------------------------------------------
__global__ __launch_bounds__(256) void gemm_bf16_bt_vt(const unsigned short* __restrict__ A,
                                                       const unsigned short* __restrict__ Bt,
                                                       unsigned short* __restrict__ Ct,
                                                       int M, int N, int K, int ldct) {
  __shared__ unsigned short As[BM * BK];
  __shared__ unsigned short Bs[BN * BK];

  const int tid = threadIdx.x;
  const int lane = tid & 63;
  const int wave = tid >> 6;
  const int m0 = blockIdx.y * BM;
  const int n0 = blockIdx.x * BN;

  const int qm = (wave >> 1) * 64;
  const int qn = (wave & 1) * 64;
  const int l15 = lane & 15;
  const int quad = lane >> 4;

  const int st_row = lane >> 2;
  const int st_col = (lane & 3) * 8;

  f32x4 acc[4][4] = {};

  for (int k0 = 0; k0 < K; k0 += BK) {
#pragma unroll
    for (int p = 0; p < 2; ++p) {
      const int rb = p * 64 + wave * 16;
      gload16(A + (size_t)(m0 + rb + st_row) * K + k0 + st_col, &As[rb * BK]);
      gload16(Bt + (size_t)(n0 + rb + st_row) * K + k0 + st_col, &Bs[rb * BK]);
    }
    __syncthreads();

    s16x8 a[4], b[4];
#pragma unroll
    for (int i = 0; i < 4; ++i)
      a[i] = *(const s16x8*)&As[(qm + i * 16 + l15) * BK + quad * 8];
#pragma unroll
    for (int j = 0; j < 4; ++j)
      b[j] = *(const s16x8*)&Bs[(qn + j * 16 + l15) * BK + quad * 8];
#pragma unroll
    for (int i = 0; i < 4; ++i)
#pragma unroll
      for (int j = 0; j < 4; ++j)
        acc[i][j] = __builtin_amdgcn_mfma_f32_16x16x32_bf16(a[i], b[j], acc[i][j], 0, 0, 0);
    __syncthreads();
  }

  // transposed store: Ct[n][m], 4 consecutive m per lane -> 8B bf16 store
#pragma unroll
  for (int i = 0; i < 4; ++i) {
    const int row_base = m0 + qm + i * 16 + quad * 4;  // m
#pragma unroll
    for (int j = 0; j < 4; ++j) {
      const int col = n0 + qn + j * 16 + l15;          // n
      ushort4 u;
      u.x = f2bf(acc[i][j][0]); u.y = f2bf(acc[i][j][1]);
      u.z = f2bf(acc[i][j][2]); u.w = f2bf(acc[i][j][3]);
      *(ushort4*)(Ct + (size_t)col * ldct + row_base) = u;
    }
  }
}

// ---------------------------------------------------------------------------
// Split-precision bf16 MFMA GEMM: C = (Ahi+Alo) * (Bhi+Blo)^T, dropping lo*lo.
// ---------------------------------------------------------------------------
__global__ __launch_bounds__(256) void gemm_split_bt(const unsigned short* __restrict__ Ahi,
                                                     const unsigned short* __restrict__ Alo,
                                                     const unsigned short* __restrict__ Bhi,
                                                     const unsigned short* __restrict__ Blo,
                                                     float* __restrict__ C,
                                                     int M, int N, int K, int ldc) {
  __shared__ unsigned short AsH[BM * BK];
  __shared__ unsigned short AsL[BM * BK];
  __shared__ unsigned short BsH[BN * BK];
  __shared__ unsigned short BsL[BN * BK];

  const int tid = threadIdx.x;
  const int lane = tid & 63;
  const int wave = tid >> 6;
  const int m0 = blockIdx.y * BM;
  const int n0 = blockIdx.x * BN;

  const int qm = (wave >> 1) * 64;
  const int qn = (wave & 1) * 64;
  const int l15 = lane & 15;
  const int quad = lane >> 4;

  const int st_row = lane >> 2;
  const int st_col = (lane & 3) * 8;

  f32x4 acc[4][4] = {};

  for (int k0 = 0; k0 < K; k0 += BK) {
#pragma unroll
    for (int p = 0; p < 2; ++p) {
      const int rb = p * 64 + wave * 16;
      const size_t aoff = (size_t)(m0 + rb + st_row) * K + k0 + st_col;
      const size_t boff = (size_t)(n0 + rb + st_row) * K + k0 + st_col;
      gload16(Ahi + aoff, &AsH[rb * BK]);
      gload16(Alo + aoff, &AsL[rb * BK]);
      gload16(Bhi + boff, &BsH[rb * BK]);
      gload16(Blo + boff, &BsL[rb * BK]);
    }
    __syncthreads();

    s16x8 ah[4], al[4], bh[4], bl[4];
#pragma unroll
    for (int i = 0; i < 4; ++i) {
      const int ro = (qm + i * 16 + l15) * BK + quad * 8;
      ah[i] = *(const s16x8*)&AsH[ro];
      al[i] = *(const s16x8*)&AsL[ro];
    }
#pragma unroll
    for (int j = 0; j < 4; ++j) {
      const int ro = (qn + j * 16 + l15) * BK + quad * 8;
      bh[j] = *(const s16x8*)&BsH[ro];
      bl[j] = *(const s16x8*)&BsL[ro];
    }
#pragma unroll
    for (int i = 0; i < 4; ++i)
#pragma unroll
      for (int j = 0; j < 4; ++j) {
        acc[i][j] = __builtin_amdgcn_mfma_f32_16x16x32_bf16(ah[i], bh[j], acc[i][j], 0, 0, 0);
        acc[i][j] = __builtin_amdgcn_mfma_f32_16x16x32_bf16(ah[i], bl[j], acc[i][j], 0, 0, 0);
        acc[i][j] = __builtin_amdgcn_mfma_f32_16x16x32_bf16(al[i], bh[j], acc[i][j], 0, 0, 0);
      }
    __syncthreads();
  }

#pragma unroll
  for (int i = 0; i < 4; ++i) {
    const int row_base = m0 + qm + i * 16 + quad * 4;
#pragma unroll
    for (int j = 0; j < 4; ++j) {
      const int col = n0 + qn + j * 16 + l15;
#pragma unroll
      for (int r = 0; r < 4; ++r)
        C[(size_t)(row_base + r) * ldc + col] = acc[i][j][r];
    }
  }
}

// ---------------------------------------------------------------------------
// Fused RMSNorm + RoPE on packed fp32 QK [S][3072], emitting SPLIT bf16:
// q (pre-scaled by QK_SCALE) -> qh/ql [S][2048]; k -> kh/kl [S][1024].
// ---------------------------------------------------------------------------
__global__ __launch_bounds__(128) void rmsnorm_rope_split(const float* __restrict__ qk,
                                                          const float* __restrict__ cosb,
                                                          const float* __restrict__ sinb,
                                                          unsigned short* __restrict__ qh,
                                                          unsigned short* __restrict__ ql,
                                                          unsigned short* __restrict__ kh,
                                                          unsigned short* __restrict__ kl) {
  const int s = blockIdx.x;
  const int hh = blockIdx.y;
  const bool is_q = (hh < 16);
  const int col = is_q ? hh * HD : 2048 + (hh - 16) * HD;
  const int t = threadIdx.x;  // 0..127 = d

  const float* row = qk + (size_t)s * 3072 + col;
  const float v = row[t];

  __shared__ float sv[HD];
  __shared__ float red[HD];
  sv[t] = v;
  red[t] = v * v;
  __syncthreads();
#pragma unroll
  for (int off = 64; off > 0; off >>= 1) {
    if (t < off) red[t] += red[t + off];
    __syncthreads();
  }
  const float r = rsqrtf(red[0] / (float)HD + EPS);

  const float xn = v * r;
  const float other = sv[t ^ 64] * r;
  const float rot = (t < 64) ? -other : other;
  const float c = cosb[(size_t)s * HD + t];
  const float sn = sinb[(size_t)s * HD + t];
  float o = xn * c + rot * sn;
  if (is_q) o *= QK_SCALE;

  const unsigned short hu = f2bf(o);
  const unsigned short lu = f2bf(o - bf2f(hu));
  if (is_q) {
    qh[(size_t)s * 2048 + hh * HD + t] = hu;
    ql[(size_t)s * 2048 + hh * HD + t] = lu;
  } else {
    kh[(size_t)s * 1024 + (hh - 16) * HD + t] = hu;
    kl[(size_t)s * 1024 + (hh - 16) * HD + t] = lu;
  }
}

// ---------------------------------------------------------------------------
// Flash attention, MFMA. grid (S/64, NH) = 512 blocks, block 256
// (4 waves x 16 Q-rows each). Q hi/lo fragments live in REGISTERS (loaded
// once, direct from global); LDS holds only K hi/lo + Vt + Pt = 62.4 KB ->
// 2 blocks/CU -> 2 waves/SIMD so MFMA overlaps softmax/staging (m114).
// QK^T: split bf16 (3 MFMAs) for fp32-grade scores; PV: plain bf16.
// Pt is same-wave produce/consume (DS ops wave-ordered) -> no 3rd barrier.
// ---------------------------------------------------------------------------
#define FA_M 64
#define FA_N 64

__global__ __launch_bounds__(256) void attn_flash_mfma(const unsigned short* __restrict__ qh,
                                                       const unsigned short* __restrict__ ql,
                                                       const unsigned short* __restrict__ kh,
                                                       const unsigned short* __restrict__ kl,
                                                       const unsigned short* __restrict__ vt,
                                                       unsigned short* __restrict__ out) {
  const int h = blockIdx.y;
  const int kvh = h >> 1;
  const int m0 = blockIdx.x * FA_M;
  const int tid = threadIdx.x;
  const int lane = tid & 63;
  const int wave = tid >> 6;
  const int l15 = lane & 15;
  const int quad = lane >> 4;

  __shared__ unsigned short Kh[64][136];   // [key][d]
  __shared__ unsigned short Kl[64][136];
  __shared__ unsigned short Vt[128][72];   // [d][key]
  __shared__ unsigned short Pt[64][72];    // [qrow][key]

  // ---- Q fragments in registers (A-layout: row=l15, k=quad*8..), once ----
  const int qrow = m0 + wave * 16 + l15;
  s16x8 qah[4], qal[4];
#pragma unroll
  for (int ks = 0; ks < 4; ++ks) {
    const size_t off = (size_t)qrow * 2048 + h * HD + ks * 32 + quad * 8;
    qah[ks] = *(const s16x8*)(qh + off);
    qal[ks] = *(const s16x8*)(ql + off);
  }

  f32x4 O[8] = {};
  float m_i[4], l_i[4];
#pragma unroll
  for (int r = 0; r < 4; ++r) { m_i[r] = -1e30f; l_i[r] = 0.f; }

  for (int n0 = 0; n0 < S; n0 += FA_N) {
    __syncthreads();  // protect Kh/Kl/Vt from previous iteration's readers
    // ---- stage K hi/lo + Vt ----
    for (int idx = tid; idx < 64 * 16; idx += 256) {
      const int r = idx >> 4;
      const int c = (idx & 15) * 8;
      *(s16x8*)&Kh[r][c] = *(const s16x8*)(kh + (size_t)(n0 + r) * 1024 + kvh * HD + c);
      *(s16x8*)&Kl[r][c] = *(const s16x8*)(kl + (size_t)(n0 + r) * 1024 + kvh * HD + c);
    }
    for (int idx = tid; idx < 128 * 8; idx += 256) {
      const int r = idx >> 3;
      const int c = (idx & 7) * 8;
      *(s16x8*)&Vt[r][c] = *(const s16x8*)(vt + (size_t)(kvh * HD + r) * 2048 + n0 + c);
    }
    __syncthreads();

    // ---- S = Q K^T, split precision ----
    f32x4 sacc[4] = {};
#pragma unroll
    for (int ks = 0; ks < 4; ++ks) {
      s16x8 bh[4], bl[4];
#pragma unroll
      for (int j = 0; j < 4; ++j) {
        bh[j] = *(const s16x8*)&Kh[j * 16 + l15][ks * 32 + quad * 8];
        bl[j] = *(const s16x8*)&Kl[j * 16 + l15][ks * 32 + quad * 8];
      }
#pragma unroll
      for (int j = 0; j < 4; ++j) {
        sacc[j] = __builtin_amdgcn_mfma_f32_16x16x32_bf16(qah[ks], bh[j], sacc[j], 0, 0, 0);
        sacc[j] = __builtin_amdgcn_mfma_f32_16x16x32_bf16(qah[ks], bl[j], sacc[j], 0, 0, 0);
        sacc[j] = __builtin_amdgcn_mfma_f32_16x16x32_bf16(qal[ks], bh[j], sacc[j], 0, 0, 0);
      }
    }

    // ---- online softmax; C-layout row = quad*4+r, col = l15+16j ----
#pragma unroll
    for (int r = 0; r < 4; ++r) {
      float mt = fmaxf(fmaxf(sacc[0][r], sacc[1][r]), fmaxf(sacc[2][r], sacc[3][r]));
      mt = fmaxf(mt, __shfl_xor(mt, 1));
      mt = fmaxf(mt, __shfl_xor(mt, 2));
      mt = fmaxf(mt, __shfl_xor(mt, 4));
      mt = fmaxf(mt, __shfl_xor(mt, 8));
      const float mnew = fmaxf(m_i[r], mt);
      const float alpha = __expf(m_i[r] - mnew);
      m_i[r] = mnew;
      float p0 = __expf(sacc[0][r] - mnew);
      float p1 = __expf(sacc[1][r] - mnew);
      float p2 = __expf(sacc[2][r] - mnew);
      float p3 = __expf(sacc[3][r] - mnew);
      float ls = p0 + p1 + p2 + p3;
      ls += __shfl_xor(ls, 1);
      ls += __shfl_xor(ls, 2);
      ls += __shfl_xor(ls, 4);
      ls += __shfl_xor(ls, 8);
      l_i[r] = l_i[r] * alpha + ls;
#pragma unroll
      for (int jd = 0; jd < 8; ++jd) O[jd][r] *= alpha;
      const int prow = wave * 16 + quad * 4 + r;
      Pt[prow][l15 + 0]  = f2bf(p0);
      Pt[prow][l15 + 16] = f2bf(p1);
      Pt[prow][l15 + 32] = f2bf(p2);
      Pt[prow][l15 + 48] = f2bf(p3);
    }
    // no barrier: Pt rows are produced and consumed by the same wave,
    // and DS ops within a wave are ordered.

    // ---- O += P V ----
#pragma unroll
    for (int ks2 = 0; ks2 < 2; ++ks2) {
      s16x8 pa = *(const s16x8*)&Pt[wave * 16 + l15][ks2 * 32 + quad * 8];
      s16x8 vb[8];
#pragma unroll
      for (int jd = 0; jd < 8; ++jd)
        vb[jd] = *(const s16x8*)&Vt[jd * 16 + l15][ks2 * 32 + quad * 8];
#pragma unroll
      for (int jd = 0; jd < 8; ++jd)
        O[jd] = __builtin_amdgcn_mfma_f32_16x16x32_bf16(pa, vb[jd], O[jd], 0, 0, 0);
    }
  }

  // ---- epilogue: normalize, bf16 store ----
#pragma unroll
  for (int r = 0; r < 4; ++r) {
    const float inv = 1.f / l_i[r];
    const int row = m0 + wave * 16 + quad * 4 + r;
#pragma unroll
    for (int jd = 0; jd < 8; ++jd)
      out[(size_t)row * 2048 + h * HD + jd * 16 + l15] = f2bf(O[jd][r] * inv);
  }
}

// ---------------------------------------------------------------------------
extern "C" void kernel_launch(void* const* d_in, const int* in_sizes, int n_in,
                              void* d_out, int out_size, void* d_ws, size_t ws_size,
                              hipStream_t stream) {
  const float* hidden = (const float*)d_in[0];  // [S][HID]
  const float* cosb   = (const float*)d_in[1];  // [S][HD]
  const float* sinb   = (const float*)d_in[2];  // [S][HD]
  const float* wq     = (const float*)d_in[3];  // [HID][2048]
  const float* wk     = (const float*)d_in[4];  // [HID][1024]
  const float* wv     = (const float*)d_in[5];  // [HID][1024]
  const float* wo     = (const float*)d_in[6];  // [2048][HID]
  float* out = (float*)d_out;                   // [S][HID]

  // Workspace map (72 MB, regions reused once dead):
  char* w = (char*)d_ws;
  float* qk_buf           = (float*)(w);                          //  0-24 MB fp32 [S][3072]
  unsigned short* wqkT_hi = (unsigned short*)(w + (24u << 20));   // 24-36 (dead after QK gemm)
  unsigned short* wqkT_lo = (unsigned short*)(w + (36u << 20));   // 36-48 (dead after QK gemm)
  unsigned short* hid_hi  = (unsigned short*)(w + (48u << 20));   // 48-56 (dead after V gemm)
  unsigned short* hid_lo  = (unsigned short*)(w + (56u << 20));   // 56-64 (dead after QK gemm)
  unsigned short* vt_b    = (unsigned short*)(w + (64u << 20));   // 64-68 V^T bf16 [1024][2048]
  unsigned short* wvT     = (unsigned short*)(w + (68u << 20));   // 68-72
  // reuse after QK gemm:
  unsigned short* q_hi    = (unsigned short*)(w + (24u << 20));   // 24-32 [S][2048]
  unsigned short* q_lo    = (unsigned short*)(w + (32u << 20));   // 32-40
  unsigned short* k_hi    = (unsigned short*)(w + (40u << 20));   // 40-44 [S][1024]
  unsigned short* k_lo    = (unsigned short*)(w + (44u << 20));   // 44-48
  // reuse after V gemm:
  unsigned short* woT     = (unsigned short*)(w + (48u << 20));   // 48-56 [2048][2048]
  unsigned short* a_b     = (unsigned short*)(w + (56u << 20));   // 56-64 [S][2048]

  dim3 blk(256);

  // prologue
  f32_to_bf16_split<<<dim3((S * HID / 4 + 255) / 256), blk, 0, stream>>>(hidden, hid_hi, hid_lo, S * HID / 4);
  transpose_to_bf16_split<<<dim3(32, 32), blk, 0, stream>>>(wq, wqkT_hi, wqkT_lo, HID, 2048);
  transpose_to_bf16_split<<<dim3(16, 32), blk, 0, stream>>>(wk, wqkT_hi + (size_t)2048 * 2048,
                                                            wqkT_lo + (size_t)2048 * 2048, HID, 1024);
  transpose_to_bf16<<<dim3(16, 32), blk, 0, stream>>>(wv, wvT, 2048, 1024);

  // QK projection (split precision) -> fp32 [S][3072]
  gemm_split_bt<<<dim3(3072 / BN, S / BM), blk, 0, stream>>>(hid_hi, hid_lo, wqkT_hi, wqkT_lo,
                                                             qk_buf, S, 3072, HID, 3072);

  // V projection -> transposed bf16 [1024][2048]
  gemm_bf16_bt_vt<<<dim3(1024 / BN, S / BM), blk, 0, stream>>>(hid_hi, wvT, vt_b, S, 1024, HID, 2048);

  // wo transpose into dead hid_hi region (after V gemm in stream order)
  transpose_to_bf16<<<dim3(32, 32), blk, 0, stream>>>(wo, woT, 2048, HID);

  // RMSNorm + RoPE -> split bf16 q/k (q pre-scaled)
  rmsnorm_rope_split<<<dim3(S, 24), dim3(128), 0, stream>>>(qk_buf, cosb, sinb, q_hi, q_lo, k_hi, k_lo);

  // MFMA flash attention -> bf16 [S][2048]
  attn_flash_mfma<<<dim3(S / FA_M, NH), blk, 0, stream>>>(q_hi, q_lo, k_hi, k_lo, vt_b, a_b);

  // output projection -> fp32 out
  gemm_bf16_bt<float><<<dim3(HID / BN, S / BM), blk, 0, stream>>>(a_b, woT, out, S, HID, 2048, HID);
}